// Round 6
// baseline (807.007 us; speedup 1.0000x reference)
//
#include <hip/hip_runtime.h>
#include <hip/hip_bf16.h>

#define D_ 256
#define NH_ 8
#define HD_ 32
#define NL_ 4
#define NP_ 4
#define DFF_ 1024
#define BS_ 8
#define LQ_ 300
#define LV_ 20197
#define NQ_ (BS_*LQ_)          // 2400
#define NSRC_ (BS_*LV_*D_)     // 41,363,456 floats

__device__ __forceinline__ float u2f(unsigned int u) {
    union { unsigned int i; float f; } v; v.i = u << 16; return v.f;
}
__device__ __forceinline__ float lo2f(unsigned int u) {   // low bf16 of a pair
    union { unsigned int i; float f; } v; v.i = u << 16; return v.f;
}
__device__ __forceinline__ float hi2f(unsigned int u) {   // high bf16 of a pair
    union { unsigned int i; float f; } v; v.i = u & 0xffff0000u; return v.f;
}
__device__ __forceinline__ unsigned short f2bf_bits(float f) {
    __hip_bfloat16 b = __float2bfloat16(f);
    union { __hip_bfloat16 b; unsigned short u; } v; v.b = b; return v.u;
}

// acc += dot(w4[c], a4[c]) over 4 floats
#define DOT4(accum, wv, ap) do { \
    float4 _a = *(const float4*)(ap); \
    accum += wv.x*_a.x + wv.y*_a.y + wv.z*_a.z + wv.w*_a.w; } while(0)

// ---------------- 0. fp32 -> bf16 conversion of src (and Wv) ----------------
__global__ __launch_bounds__(256) void cvt_bf16_kernel(
    const float* __restrict__ src, const float* __restrict__ wv,
    unsigned short* __restrict__ vbf, unsigned short* __restrict__ wbf)
{
    const int nsrc4 = NSRC_/4;
    const int total4 = nsrc4 + (D_*D_)/4;
    for (int i = blockIdx.x*256 + threadIdx.x; i < total4; i += gridDim.x*256) {
        float4 v;
        if (i < nsrc4) v = ((const float4*)src)[i];
        else           v = ((const float4*)wv)[i - nsrc4];
        ushort4 o;
        o.x = f2bf_bits(v.x); o.y = f2bf_bits(v.y);
        o.z = f2bf_bits(v.z); o.w = f2bf_bits(v.w);
        if (i < nsrc4) ((ushort4*)vbf)[i] = o;
        else           ((ushort4*)wbf)[i - nsrc4] = o;
    }
}

// ---------------- 1. QKV projection, 512 threads (2 row-halves share weights) ----
__global__ __launch_bounds__(512) void qkv_kernel(
    const float* __restrict__ tgt, const float* __restrict__ qp,
    const float* __restrict__ w, const float* __restrict__ bias,
    float* __restrict__ qh, float* __restrict__ kh, float* __restrict__ vh)
{
    __shared__ float arow[8][D_];
    const int t = threadIdx.x, m0 = blockIdx.x * 8, pass = blockIdx.y;
    const int tt = t & 255, half = t >> 8;
    for (int i = t; i < 8*D_; i += 512) {
        int r = i >> 8, c = i & 255;
        float tv = tgt[(m0+r)*D_ + c];
        arow[r][c] = (pass == 2) ? tv : tv + qp[(m0+r)*D_ + c];
    }
    __syncthreads();
    const float4* w4 = (const float4*)(w + (pass*256 + tt)*D_);
    float acc[4] = {0,0,0,0};
    for (int c = 0; c < 64; ++c) {
        float4 wv = w4[c];
#pragma unroll
        for (int r = 0; r < 4; ++r) DOT4(acc[r], wv, &arow[half*4+r][c*4]);
    }
    float bb = bias[pass*256 + tt];
    float* dst = (pass == 0) ? qh : (pass == 1) ? kh : vh;
    for (int r = 0; r < 4; ++r) dst[(m0+half*4+r)*D_ + tt] = acc[r] + bb;
}

// ---------------- 2. Self attention (no inner barriers; grid.y=15) ----------------
__global__ __launch_bounds__(256) void attn_kernel(
    const float* __restrict__ qh, const float* __restrict__ kh,
    const float* __restrict__ vh, float* __restrict__ sa)
{
    __shared__ unsigned short khl[LQ_][HD_+2];
    __shared__ unsigned short vhl[LQ_][HD_+2];
    __shared__ float sc[4][LQ_];
    __shared__ float qbuf[4][HD_];
    const int b = blockIdx.x >> 3, h = blockIdx.x & 7, chunk = blockIdx.y;
    const int t = threadIdx.x, w = t >> 6, lane = t & 63;
    for (int i = t; i < LQ_*HD_; i += 256) {
        int kq = i >> 5, d = i & 31;
        khl[kq][d] = f2bf_bits(kh[(b*LQ_ + kq)*D_ + h*HD_ + d]);
        vhl[kq][d] = f2bf_bits(vh[(b*LQ_ + kq)*D_ + h*HD_ + d]);
    }
    __syncthreads();
    const float scale = 0.17677669529663687f;  // 1/sqrt(32)
    for (int qi = 0; qi < 5; ++qi) {
        const int q = chunk*20 + w*5 + qi;
        if (lane < HD_) qbuf[w][lane] = qh[(b*LQ_ + q)*D_ + h*HD_ + lane];
        float qv[HD_];
#pragma unroll
        for (int d2 = 0; d2 < HD_; ++d2) qv[d2] = qbuf[w][d2];
        float mx = -1e30f;
        for (int k = lane; k < LQ_; k += 64) {
            float s = 0.f;
#pragma unroll
            for (int d2 = 0; d2 < HD_; ++d2) s += qv[d2]*u2f(khl[k][d2]);
            s *= scale;
            sc[w][k] = s;
            mx = fmaxf(mx, s);
        }
#pragma unroll
        for (int off = 32; off; off >>= 1) mx = fmaxf(mx, __shfl_xor(mx, off));
        float lsum = 0.f;
        for (int k = lane; k < LQ_; k += 64) {
            float e = __expf(sc[w][k] - mx);
            sc[w][k] = e; lsum += e;
        }
#pragma unroll
        for (int off = 32; off; off >>= 1) lsum += __shfl_xor(lsum, off);
        const int d = lane & 31, half = lane >> 5;
        float acc = 0.f;
        for (int k = half*150; k < half*150 + 150; ++k) acc += sc[w][k]*u2f(vhl[k][d]);
        acc += __shfl_down(acc, 32);
        if (lane < 32) sa[(b*LQ_ + q)*D_ + h*HD_ + d] = acc / lsum;
    }
}

// ---------------- 3/6. proj + residual + LayerNorm (512 thr, 1-barrier LN) -------
__global__ __launch_bounds__(512) void proj_res_ln_kernel(
    const float* __restrict__ A, const float* __restrict__ W,
    const float* __restrict__ bias, const float* __restrict__ res,
    const float* __restrict__ gw, const float* __restrict__ gb,
    float* __restrict__ out)
{
    __shared__ float arow[8][D_];
    __shared__ float2 part[8][4];
    const int t = threadIdx.x, m0 = blockIdx.x * 8;
    const int tt = t & 255, half = t >> 8;
    const int w = t >> 6, lane = t & 63;
    for (int i = t; i < 8*D_; i += 512)
        arow[i >> 8][i & 255] = A[(m0 + (i >> 8))*D_ + (i & 255)];
    __syncthreads();
    float acc[4] = {0,0,0,0};
    const float4* w4 = (const float4*)(W + tt*D_);
    for (int c = 0; c < 64; ++c) {
        float4 wv = w4[c];
#pragma unroll
        for (int r = 0; r < 4; ++r) DOT4(acc[r], wv, &arow[half*4+r][c*4]);
    }
    const float bb = bias[tt], gwv = gw[tt], gbv = gb[tt];
    float v[4];
#pragma unroll
    for (int r = 0; r < 4; ++r) {
        v[r] = acc[r] + bb + res[(m0+half*4+r)*D_+tt];
        float s = v[r], ss = v[r]*v[r];
#pragma unroll
        for (int off = 32; off; off >>= 1) {
            s += __shfl_xor(s, off); ss += __shfl_xor(ss, off);
        }
        if (lane == 0) part[w][r] = make_float2(s, ss);
    }
    __syncthreads();
#pragma unroll
    for (int r = 0; r < 4; ++r) {
        float2 p0 = part[half*4+0][r], p1 = part[half*4+1][r],
               p2 = part[half*4+2][r], p3 = part[half*4+3][r];
        float mean = (p0.x+p1.x+p2.x+p3.x) * (1.0f/256.0f);
        float ex2  = (p0.y+p1.y+p2.y+p3.y) * (1.0f/256.0f);
        float var  = ex2 - mean*mean;
        out[(m0+half*4+r)*D_+tt] = (v[r]-mean) * rsqrtf(var + 1e-5f) * gwv + gbv;
    }
}

// ---------------- 4. sampling offsets / attention weights / loc (512 thr) --------
__global__ __launch_bounds__(512) void samp_params_kernel(
    const float* __restrict__ x1, const float* __restrict__ qp,
    const float* __restrict__ so_w, const float* __restrict__ so_b,
    const float* __restrict__ aw_w, const float* __restrict__ aw_b,
    const float* __restrict__ refp,
    float* __restrict__ loc_out, float* __restrict__ aw_out)
{
    __shared__ float qrow[8][D_];
    __shared__ float logits[8][128];
    const int t = threadIdx.x, m0 = blockIdx.x * 8;
    const int tt = t & 255, half = t >> 8;
    for (int i = t; i < 8*D_; i += 512) {
        int r = i >> 8, c = i & 255;
        qrow[r][c] = x1[(m0+r)*D_ + c] + qp[(m0+r)*D_ + c];
    }
    __syncthreads();
    {   // offsets -> loc
        float acc[4] = {0,0,0,0};
        const float4* w4 = (const float4*)(so_w + tt*D_);
        for (int c = 0; c < 64; ++c) {
            float4 wv = w4[c];
#pragma unroll
            for (int r = 0; r < 4; ++r) DOT4(acc[r], wv, &qrow[half*4+r][c*4]);
        }
        const float ob = so_b[tt];
        const int c_ = tt & 1, l_ = (tt >> 3) & 3;
        float nrm;
        if (c_ == 0) nrm = (l_==0)?152.f:(l_==1)?76.f:(l_==2)?38.f:19.f;
        else         nrm = (l_==0)?100.f:(l_==1)?50.f:(l_==2)?25.f:13.f;
        for (int r = 0; r < 4; ++r) {
            int m = m0 + half*4 + r;
            float off = acc[r] + ob;
            loc_out[m*256 + tt] = refp[(m*NL_ + l_)*2 + c_] + off / nrm;
        }
    }
    if (tt < 128) {  // attention-weight logits (each half does its 4 rows)
        float acc[4] = {0,0,0,0};
        const float4* w4 = (const float4*)(aw_w + tt*D_);
        for (int c = 0; c < 64; ++c) {
            float4 wv = w4[c];
#pragma unroll
            for (int r = 0; r < 4; ++r) DOT4(acc[r], wv, &qrow[half*4+r][c*4]);
        }
        const float ab = aw_b[tt];
        for (int r = 0; r < 4; ++r) logits[half*4+r][tt] = acc[r] + ab;
    }
    __syncthreads();
    if (tt < 128) {  // softmax over the 16 (l,p) per head
        const int g0 = (tt >> 4) << 4;
        for (int r = 0; r < 4; ++r) {
            const int row = half*4 + r;
            float mx = -1e30f;
            for (int j = 0; j < 16; ++j) mx = fmaxf(mx, logits[row][g0+j]);
            float s = 0.f;
            for (int j = 0; j < 16; ++j) s += __expf(logits[row][g0+j] - mx);
            aw_out[(m0+row)*128 + tt] = __expf(logits[row][tt] - mx) / s;
        }
    }
}

// ---------------- 5. deformable sampling gather (bf16) ----------------
// grid (2400, 2): y picks 4 heads. XCD-aware remap: m=(bid&7)*300+(bid>>3) puts
// all queries of batch b on XCD b -> levels 1-3 (2.6MB/batch) go L2-resident.
// Wave reads a full 512B row per (pt,corner): lane owns 4 channels via uint2.
__global__ __launch_bounds__(256) void samp_fuse_bf16_kernel(
    const unsigned short* __restrict__ vbf,
    const float* __restrict__ loc_f, const float* __restrict__ aw_f,
    float* __restrict__ svec_g, float* __restrict__ wsum_g)
{
    __shared__ int   cidx[128][4];      // clamped corner row index
    __shared__ float cwt[128][4];       // aw * bilinear weight (0 if invalid)
    const int t = threadIdx.x;
    const int m = (blockIdx.x & 7)*LQ_ + (blockIdx.x >> 3);   // bijective remap
    const int b = blockIdx.x & 7;

    if (t < 128) {   // t = h*16 + l*4 + p
        const int l = (t >> 2) & 3;
        const int HS[4] = {100,50,25,13}, WS[4] = {152,76,38,19}, S0[4] = {0,15200,19000,19950};
        const int Hh = HS[l], Ww = WS[l], s0 = S0[l];
        const float aw = aw_f[m*128 + t];
        const float x = loc_f[m*256 + 2*t]*Ww - 0.5f;
        const float y = loc_f[m*256 + 2*t + 1]*Hh - 0.5f;
        const float x0f = floorf(x), y0f = floorf(y);
        const int x0 = (int)x0f, y0 = (int)y0f;
        const float fx = x - x0f, fy = y - y0f;
        const int   cx[4] = {x0, x0+1, x0,   x0+1};
        const int   cy[4] = {y0, y0,   y0+1, y0+1};
        const float cw[4] = {(1.f-fx)*(1.f-fy), fx*(1.f-fy), (1.f-fx)*fy, fx*fy};
        float sw = 0.f;
#pragma unroll
        for (int j = 0; j < 4; ++j) {
            const bool valid = (cx[j] >= 0) & (cx[j] < Ww) & (cy[j] >= 0) & (cy[j] < Hh);
            cidx[t][j] = valid ? (s0 + cy[j]*Ww + cx[j]) : s0;   // clamped, weight 0
            float wv = valid ? aw*cw[j] : 0.f;
            cwt[t][j] = wv;
            sw += wv;
        }
#pragma unroll
        for (int off = 8; off; off >>= 1) sw += __shfl_xor(sw, off);
        if (blockIdx.y == 0 && (t & 15) == 0) wsum_g[m*NH_ + (t >> 4)] = sw;
    }
    __syncthreads();

    // gather: group g=t>>6 -> head; lane owns channels 4*lane..4*lane+3 (uint2)
    const int g = t >> 6, lane = t & 63;
    const int h = blockIdx.y*4 + g;
    const uint2* sp = (const uint2*)(vbf + (size_t)b*LV_*D_);
    float a0=0.f,a1=0.f,a2=0.f,a3=0.f;   // corners 0,2
    float b0=0.f,b1=0.f,b2=0.f,b3=0.f;   // corners 1,3
#pragma unroll 4
    for (int s = 0; s < 16; ++s) {
        const int base = h*16 + s;
        const int   i0 = cidx[base][0], i1 = cidx[base][1],
                    i2 = cidx[base][2], i3 = cidx[base][3];
        const float w0 = cwt[base][0], w1 = cwt[base][1],
                    w2 = cwt[base][2], w3 = cwt[base][3];
        const uint2 u0 = sp[(size_t)i0*64 + lane];
        const uint2 u1 = sp[(size_t)i1*64 + lane];
        const uint2 u2 = sp[(size_t)i2*64 + lane];
        const uint2 u3 = sp[(size_t)i3*64 + lane];
        a0 += w0*lo2f(u0.x); a1 += w0*hi2f(u0.x); a2 += w0*lo2f(u0.y); a3 += w0*hi2f(u0.y);
        b0 += w1*lo2f(u1.x); b1 += w1*hi2f(u1.x); b2 += w1*lo2f(u1.y); b3 += w1*hi2f(u1.y);
        a0 += w2*lo2f(u2.x); a1 += w2*hi2f(u2.x); a2 += w2*lo2f(u2.y); a3 += w2*hi2f(u2.y);
        b0 += w3*lo2f(u3.x); b1 += w3*hi2f(u3.x); b2 += w3*lo2f(u3.y); b3 += w3*hi2f(u3.y);
    }
    *(float4*)&svec_g[(size_t)m*(NH_*D_) + h*D_ + 4*lane] =
        make_float4(a0+b0, a1+b1, a2+b2, a3+b3);
}

// ---------------- 5c. per-head value projection: vo = Wv_h @ svec_h + b*wsum ----
__global__ __launch_bounds__(256) void vproj_kernel(
    const float* __restrict__ svec_g, const float* __restrict__ wsum_g,
    const unsigned short* __restrict__ wbf, const float* __restrict__ vpb,
    float* __restrict__ vo)
{
    __shared__ float sv[4][NH_*D_];    // 32 KB
    const int t = threadIdx.x, m0 = blockIdx.x * 4;
    for (int i = t; i < 4*NH_*D_; i += 256)
        sv[i >> 11][i & 2047] = svec_g[(size_t)m0*(NH_*D_) + i];
    __syncthreads();
    const int h = t >> 5;
    const ushort4* w4 = (const ushort4*)(wbf + t*D_);
    float a0 = 0.f, a1 = 0.f, a2 = 0.f, a3 = 0.f;
    for (int c = 0; c < 64; ++c) {
        const ushort4 wq = w4[c];
        const float wx = u2f(wq.x), wy = u2f(wq.y), wz = u2f(wq.z), ww = u2f(wq.w);
        const float4 s0 = *(const float4*)&sv[0][h*D_ + c*4];
        const float4 s1 = *(const float4*)&sv[1][h*D_ + c*4];
        const float4 s2 = *(const float4*)&sv[2][h*D_ + c*4];
        const float4 s3 = *(const float4*)&sv[3][h*D_ + c*4];
        a0 += wx*s0.x + wy*s0.y + wz*s0.z + ww*s0.w;
        a1 += wx*s1.x + wy*s1.y + wz*s1.z + ww*s1.w;
        a2 += wx*s2.x + wy*s2.y + wz*s2.z + ww*s2.w;
        a3 += wx*s3.x + wy*s3.y + wz*s3.z + ww*s3.w;
    }
    const float bb = vpb[t];
    vo[(size_t)(m0+0)*D_ + t] = a0 + bb*wsum_g[(m0+0)*NH_ + h];
    vo[(size_t)(m0+1)*D_ + t] = a1 + bb*wsum_g[(m0+1)*NH_ + h];
    vo[(size_t)(m0+2)*D_ + t] = a2 + bb*wsum_g[(m0+2)*NH_ + h];
    vo[(size_t)(m0+3)*D_ + t] = a3 + bb*wsum_g[(m0+3)*NH_ + h];
}

// ---------------- 5b. fallback fp32 samp_fuse (if workspace too small) ----------
__global__ __launch_bounds__(256) void samp_fuse_f32_kernel(
    const float* __restrict__ src, const float* __restrict__ Wv,
    const float* __restrict__ vpb,
    const float* __restrict__ loc_f, const float* __restrict__ aw_f,
    float* __restrict__ vo)
{
    __shared__ float svec[NH_][D_];
    __shared__ int   cidx[128][4];
    __shared__ float cwt[128][4];
    __shared__ float wsum[NH_];
    const int m = blockIdx.x, t = threadIdx.x;
    const int b = m / LQ_;

    if (t < 128) {
        const int l = (t >> 2) & 3;
        const int HS[4] = {100,50,25,13}, WS[4] = {152,76,38,19}, S0[4] = {0,15200,19000,19950};
        const int Hh = HS[l], Ww = WS[l], s0 = S0[l];
        const float aw = aw_f[m*128 + t];
        const float x = loc_f[m*256 + 2*t]*Ww - 0.5f;
        const float y = loc_f[m*256 + 2*t + 1]*Hh - 0.5f;
        const float x0f = floorf(x), y0f = floorf(y);
        const int x0 = (int)x0f, y0 = (int)y0f;
        const float fx = x - x0f, fy = y - y0f;
        const int   cx[4] = {x0, x0+1, x0,   x0+1};
        const int   cy[4] = {y0, y0,   y0+1, y0+1};
        const float cw[4] = {(1.f-fx)*(1.f-fy), fx*(1.f-fy), (1.f-fx)*fy, fx*fy};
        float sw = 0.f;
#pragma unroll
        for (int jj = 0; jj < 4; ++jj) {
            const bool valid = (cx[jj] >= 0) & (cx[jj] < Ww) & (cy[jj] >= 0) & (cy[jj] < Hh);
            cidx[t][jj] = valid ? (s0 + cy[jj]*Ww + cx[jj]) : s0;
            float wv = valid ? aw*cw[jj] : 0.f;
            cwt[t][jj] = wv;
            sw += wv;
        }
#pragma unroll
        for (int off = 8; off; off >>= 1) sw += __shfl_xor(sw, off);
        if ((t & 15) == 0) wsum[t >> 4] = sw;
    }
    __syncthreads();

    const float* sb = src + (size_t)b*LV_*D_ + t;
#pragma unroll
    for (int h = 0; h < NH_; ++h) {
        float a0 = 0.f, a1 = 0.f, a2 = 0.f, a3 = 0.f;
#pragma unroll 4
        for (int s = 0; s < 16; ++s) {
            const int base = h*16 + s;
            const int   i0 = cidx[base][0], i1 = cidx[base][1],
                        i2 = cidx[base][2], i3 = cidx[base][3];
            const float w0 = cwt[base][0], w1 = cwt[base][1],
                        w2 = cwt[base][2], w3 = cwt[base][3];
            a0 += w0 * sb[(size_t)i0*D_];
            a1 += w1 * sb[(size_t)i1*D_];
            a2 += w2 * sb[(size_t)i2*D_];
            a3 += w3 * sb[(size_t)i3*D_];
        }
        svec[h][t] = (a0 + a1) + (a2 + a3);
    }
    __syncthreads();

    const int h = t >> 5;
    const float4* w4 = (const float4*)(Wv + t*D_);
    float a = 0.f;
    for (int c = 0; c < 64; ++c) {
        float4 wv = w4[c];
        DOT4(a, wv, &svec[h][c*4]);
    }
    vo[m*D_ + t] = a + vpb[t]*wsum[h];
}

// ---------------- 7. FFN layer 1 (relu), 512 threads, cc = blockIdx.y -----------
__global__ __launch_bounds__(512) void ffn1_kernel(
    const float* __restrict__ x2, const float* __restrict__ W1,
    const float* __restrict__ b1, float* __restrict__ hid)
{
    __shared__ float arow[8][D_];
    const int t = threadIdx.x, m0 = blockIdx.x * 8, cc = blockIdx.y;
    const int tt = t & 255, half = t >> 8;
    for (int i = t; i < 8*D_; i += 512)
        arow[i >> 8][i & 255] = x2[(m0 + (i >> 8))*D_ + (i & 255)];
    __syncthreads();
    const int j = cc*256 + tt;
    float acc[4] = {0,0,0,0};
    const float4* w4 = (const float4*)(W1 + j*D_);
    for (int c = 0; c < 64; ++c) {
        float4 wv = w4[c];
#pragma unroll
        for (int r = 0; r < 4; ++r) DOT4(acc[r], wv, &arow[half*4+r][c*4]);
    }
    const float bb = b1[j];
    for (int r = 0; r < 4; ++r) {
        float v = acc[r] + bb;
        hid[(m0+half*4+r)*DFF_ + j] = v > 0.f ? v : 0.f;
    }
}

// ---------------- 8. FFN layer 2 + residual + LN (512 thr, 1-barrier LN) --------
__global__ __launch_bounds__(512) void ffn2_ln_kernel(
    const float* __restrict__ hid, const float* __restrict__ W2,
    const float* __restrict__ b2, const float* __restrict__ res,
    const float* __restrict__ gw, const float* __restrict__ gb,
    float* __restrict__ out)
{
    __shared__ float hrow[8][DFF_];
    __shared__ float2 part[8][4];
    const int t = threadIdx.x, m0 = blockIdx.x * 8;
    const int tt = t & 255, half = t >> 8;
    const int w = t >> 6, lane = t & 63;
    for (int i = t; i < 8*DFF_; i += 512)
        hrow[i >> 10][i & 1023] = hid[(m0 + (i >> 10))*DFF_ + (i & 1023)];
    __syncthreads();
    float acc[4] = {0,0,0,0};
    const float4* w4 = (const float4*)(W2 + tt*DFF_);
    for (int c = 0; c < 256; ++c) {
        float4 wv = w4[c];
#pragma unroll
        for (int r = 0; r < 4; ++r) DOT4(acc[r], wv, &hrow[half*4+r][c*4]);
    }
    const float bb = b2[tt], gwv = gw[tt], gbv = gb[tt];
    float v[4];
#pragma unroll
    for (int r = 0; r < 4; ++r) {
        v[r] = acc[r] + bb + res[(m0+half*4+r)*D_+tt];
        float s = v[r], ss = v[r]*v[r];
#pragma unroll
        for (int off = 32; off; off >>= 1) {
            s += __shfl_xor(s, off); ss += __shfl_xor(ss, off);
        }
        if (lane == 0) part[w][r] = make_float2(s, ss);
    }
    __syncthreads();
#pragma unroll
    for (int r = 0; r < 4; ++r) {
        float2 p0 = part[half*4+0][r], p1 = part[half*4+1][r],
               p2 = part[half*4+2][r], p3 = part[half*4+3][r];
        float mean = (p0.x+p1.x+p2.x+p3.x) * (1.0f/256.0f);
        float ex2  = (p0.y+p1.y+p2.y+p3.y) * (1.0f/256.0f);
        float var  = ex2 - mean*mean;
        out[(m0+half*4+r)*D_+tt] = (v[r]-mean) * rsqrtf(var + 1e-5f) * gwv + gbv;
    }
}

extern "C" void kernel_launch(void* const* d_in, const int* in_sizes, int n_in,
                              void* d_out, int out_size, void* d_ws, size_t ws_size,
                              hipStream_t stream) {
    (void)in_sizes; (void)n_in; (void)out_size;
    const float* tgt  = (const float*)d_in[0];
    const float* qpos = (const float*)d_in[1];
    const float* refp = (const float*)d_in[2];
    const float* srcp = (const float*)d_in[3];
    const float* ipw  = (const float*)d_in[4];
    const float* ipb  = (const float*)d_in[5];
    const float* opw  = (const float*)d_in[6];
    const float* opb  = (const float*)d_in[7];
    const float* sow  = (const float*)d_in[8];
    const float* sob  = (const float*)d_in[9];
    const float* aww  = (const float*)d_in[10];
    const float* awb  = (const float*)d_in[11];
    const float* vpw  = (const float*)d_in[12];
    const float* vpb  = (const float*)d_in[13];
    const float* outw = (const float*)d_in[14];
    const float* outb = (const float*)d_in[15];
    const float* l1w  = (const float*)d_in[16];
    const float* l1b  = (const float*)d_in[17];
    const float* l2w  = (const float*)d_in[18];
    const float* l2b  = (const float*)d_in[19];
    const float* n1w  = (const float*)d_in[20];
    const float* n1b  = (const float*)d_in[21];
    const float* n2w  = (const float*)d_in[22];
    const float* n2b  = (const float*)d_in[23];
    const float* n3w  = (const float*)d_in[24];
    const float* n3b  = (const float*)d_in[25];

    float* wsf = (float*)d_ws;
    float* qh   = wsf;
    float* kh   = wsf + 614400;
    float* vh   = wsf + 1228800;
    float* sa   = wsf + 1843200;
    float* x1   = wsf + 2457600;
    float* vo   = wsf + 3072000;
    float* x2   = wsf + 3686400;
    float* hid  = wsf + 4300800;                       // ..6758400 floats
    unsigned short* vbf = (unsigned short*)(wsf + 6758400);            // 41,363,456 u16
    unsigned short* wbf = (unsigned short*)(wsf + 6758400 + 20681728); // 65,536 u16
    float* svec_g = wsf + 6758400 + 20681728 + 32768;  // 4,915,200 floats
    float* wsum_g = svec_g + 4915200;                  // 19,200 floats
    const size_t need_bytes = (size_t)(6758400 + 20681728 + 32768 + 4915200 + 19200) * 4;
    const bool use_bf16 = ws_size >= need_bytes;

    float* xout   = (float*)d_out;            // x   (8,300,256)
    float* locout = xout + 614400;            // loc (8,300,8,4,4,2)
    float* awout  = xout + 1228800;           // aw  (8,300,8,4,4)

    if (use_bf16)
        cvt_bf16_kernel<<<2048, 256, 0, stream>>>(srcp, vpw, vbf, wbf);
    qkv_kernel<<<dim3(NQ_/8, 3), 512, 0, stream>>>(tgt, qpos, ipw, ipb, qh, kh, vh);
    attn_kernel<<<dim3(BS_*NH_, 15), 256, 0, stream>>>(qh, kh, vh, sa);
    proj_res_ln_kernel<<<NQ_/8, 512, 0, stream>>>(sa, opw, opb, tgt, n2w, n2b, x1);
    samp_params_kernel<<<NQ_/8, 512, 0, stream>>>(x1, qpos, sow, sob, aww, awb, refp,
                                                  locout, awout);
    if (use_bf16) {
        samp_fuse_bf16_kernel<<<dim3(NQ_, 2), 256, 0, stream>>>(vbf, locout, awout,
                                                                svec_g, wsum_g);
        vproj_kernel<<<NQ_/4, 256, 0, stream>>>(svec_g, wsum_g, wbf, vpb, vo);
    } else {
        samp_fuse_f32_kernel<<<NQ_, 256, 0, stream>>>(srcp, vpw, vpb, locout, awout, vo);
    }
    proj_res_ln_kernel<<<NQ_/8, 512, 0, stream>>>(vo, outw, outb, x1, n1w, n1b, x2);
    ffn1_kernel<<<dim3(NQ_/8, 4), 512, 0, stream>>>(x2, l1w, l1b, hid);
    ffn2_ln_kernel<<<NQ_/8, 512, 0, stream>>>(hid, l2w, l2b, x2, n3w, n3b, xout);
}

// Round 7
// 689.469 us; speedup vs baseline: 1.1705x; 1.1705x over previous
//
#include <hip/hip_runtime.h>
#include <hip/hip_bf16.h>

#define D_ 256
#define NH_ 8
#define HD_ 32
#define NL_ 4
#define NP_ 4
#define DFF_ 1024
#define BS_ 8
#define LQ_ 300
#define LV_ 20197
#define NQ_ (BS_*LQ_)          // 2400
#define NSRC_ (BS_*LV_*D_)     // 41,363,456 floats

__device__ __forceinline__ float u2f(unsigned int u) {
    union { unsigned int i; float f; } v; v.i = u << 16; return v.f;
}
__device__ __forceinline__ float lo2f(unsigned int u) {   // low bf16 of a pair
    union { unsigned int i; float f; } v; v.i = u << 16; return v.f;
}
__device__ __forceinline__ float hi2f(unsigned int u) {   // high bf16 of a pair
    union { unsigned int i; float f; } v; v.i = u & 0xffff0000u; return v.f;
}
__device__ __forceinline__ unsigned short f2bf_bits(float f) {
    __hip_bfloat16 b = __float2bfloat16(f);
    union { __hip_bfloat16 b; unsigned short u; } v; v.b = b; return v.u;
}

// acc += dot(w4[c], a4[c]) over 4 floats
#define DOT4(accum, wv, ap) do { \
    float4 _a = *(const float4*)(ap); \
    accum += wv.x*_a.x + wv.y*_a.y + wv.z*_a.z + wv.w*_a.w; } while(0)

// ---------------- 0. fp32 -> bf16 conversion of src (and Wv) ----------------
__global__ __launch_bounds__(256) void cvt_bf16_kernel(
    const float* __restrict__ src, const float* __restrict__ wv,
    unsigned short* __restrict__ vbf, unsigned short* __restrict__ wbf)
{
    const int nsrc4 = NSRC_/4;
    const int total4 = nsrc4 + (D_*D_)/4;
    for (int i = blockIdx.x*256 + threadIdx.x; i < total4; i += gridDim.x*256) {
        float4 v;
        if (i < nsrc4) v = ((const float4*)src)[i];
        else           v = ((const float4*)wv)[i - nsrc4];
        ushort4 o;
        o.x = f2bf_bits(v.x); o.y = f2bf_bits(v.y);
        o.z = f2bf_bits(v.z); o.w = f2bf_bits(v.w);
        if (i < nsrc4) ((ushort4*)vbf)[i] = o;
        else           ((ushort4*)wbf)[i - nsrc4] = o;
    }
}

// ---------------- 1. QKV projection (fused tgt+query_pos), pass = blockIdx.y ----
__global__ __launch_bounds__(256) void qkv_kernel(
    const float* __restrict__ tgt, const float* __restrict__ qp,
    const float* __restrict__ w, const float* __restrict__ bias,
    float* __restrict__ qh, float* __restrict__ kh, float* __restrict__ vh)
{
    __shared__ float arow[8][D_];
    const int t = threadIdx.x, m0 = blockIdx.x * 8, pass = blockIdx.y;
    for (int r = 0; r < 8; ++r) {
        float tv = tgt[(m0+r)*D_ + t];
        arow[r][t] = (pass == 2) ? tv : tv + qp[(m0+r)*D_ + t];
    }
    __syncthreads();
    const float4* w4 = (const float4*)(w + (pass*256 + t)*D_);
    float acc[8] = {0,0,0,0,0,0,0,0};
    for (int c = 0; c < 64; ++c) {
        float4 wv = w4[c];
#pragma unroll
        for (int r = 0; r < 8; ++r) DOT4(acc[r], wv, &arow[r][c*4]);
    }
    float bb = bias[pass*256 + t];
    float* dst = (pass == 0) ? qh : (pass == 1) ? kh : vh;
    for (int r = 0; r < 8; ++r) dst[(m0+r)*D_ + t] = acc[r] + bb;
}

// ---------------- 2. Self attention (no inner barriers; grid.y=5) ----------------
__global__ __launch_bounds__(256) void attn_kernel(
    const float* __restrict__ qh, const float* __restrict__ kh,
    const float* __restrict__ vh, float* __restrict__ sa)
{
    __shared__ unsigned short khl[LQ_][HD_+2];
    __shared__ unsigned short vhl[LQ_][HD_+2];
    __shared__ float sc[4][LQ_];
    __shared__ float qbuf[4][HD_];
    const int b = blockIdx.x >> 3, h = blockIdx.x & 7, chunk = blockIdx.y;
    const int t = threadIdx.x, w = t >> 6, lane = t & 63;
    for (int i = t; i < LQ_*HD_; i += 256) {
        int kq = i >> 5, d = i & 31;
        khl[kq][d] = f2bf_bits(kh[(b*LQ_ + kq)*D_ + h*HD_ + d]);
        vhl[kq][d] = f2bf_bits(vh[(b*LQ_ + kq)*D_ + h*HD_ + d]);
    }
    __syncthreads();
    const float scale = 0.17677669529663687f;  // 1/sqrt(32)
    for (int qi = 0; qi < 15; ++qi) {
        const int q = chunk*60 + w*15 + qi;
        if (lane < HD_) qbuf[w][lane] = qh[(b*LQ_ + q)*D_ + h*HD_ + lane];
        float qv[HD_];
#pragma unroll
        for (int d2 = 0; d2 < HD_; ++d2) qv[d2] = qbuf[w][d2];
        float mx = -1e30f;
        for (int k = lane; k < LQ_; k += 64) {
            float s = 0.f;
#pragma unroll
            for (int d2 = 0; d2 < HD_; ++d2) s += qv[d2]*u2f(khl[k][d2]);
            s *= scale;
            sc[w][k] = s;
            mx = fmaxf(mx, s);
        }
#pragma unroll
        for (int off = 32; off; off >>= 1) mx = fmaxf(mx, __shfl_xor(mx, off));
        float lsum = 0.f;
        for (int k = lane; k < LQ_; k += 64) {
            float e = __expf(sc[w][k] - mx);
            sc[w][k] = e; lsum += e;
        }
#pragma unroll
        for (int off = 32; off; off >>= 1) lsum += __shfl_xor(lsum, off);
        const int d = lane & 31, half = lane >> 5;
        float acc = 0.f;
        for (int k = half*150; k < half*150 + 150; ++k) acc += sc[w][k]*u2f(vhl[k][d]);
        acc += __shfl_down(acc, 32);
        if (lane < 32) sa[(b*LQ_ + q)*D_ + h*HD_ + d] = acc / lsum;
    }
}

// ---------------- 3/6. proj + residual + LayerNorm (4 rows/block, 600 blocks) ----
__global__ __launch_bounds__(256) void proj_res_ln_kernel(
    const float* __restrict__ A, const float* __restrict__ W,
    const float* __restrict__ bias, const float* __restrict__ res,
    const float* __restrict__ gw, const float* __restrict__ gb,
    float* __restrict__ out)
{
    __shared__ float arow[4][D_];
    __shared__ float2 part[4][4];
    const int t = threadIdx.x, m0 = blockIdx.x * 4;
    const int w = t >> 6, lane = t & 63;
    for (int r = 0; r < 4; ++r) arow[r][t] = A[(m0+r)*D_ + t];
    __syncthreads();
    float acc[4] = {0,0,0,0};
    const float4* w4 = (const float4*)(W + t*D_);
    for (int c = 0; c < 64; ++c) {
        float4 wv = w4[c];
#pragma unroll
        for (int r = 0; r < 4; ++r) DOT4(acc[r], wv, &arow[r][c*4]);
    }
    const float bb = bias[t], gwv = gw[t], gbv = gb[t];
    float v[4];
#pragma unroll
    for (int r = 0; r < 4; ++r) {
        v[r] = acc[r] + bb + res[(m0+r)*D_+t];
        float s = v[r], ss = v[r]*v[r];
#pragma unroll
        for (int off = 32; off; off >>= 1) {
            s += __shfl_xor(s, off); ss += __shfl_xor(ss, off);
        }
        if (lane == 0) part[w][r] = make_float2(s, ss);
    }
    __syncthreads();
#pragma unroll
    for (int r = 0; r < 4; ++r) {
        float2 p0 = part[0][r], p1 = part[1][r], p2 = part[2][r], p3 = part[3][r];
        float mean = (p0.x+p1.x+p2.x+p3.x) * (1.0f/256.0f);
        float ex2  = (p0.y+p1.y+p2.y+p3.y) * (1.0f/256.0f);
        float var  = ex2 - mean*mean;
        out[(m0+r)*D_+t] = (v[r]-mean) * rsqrtf(var + 1e-5f) * gwv + gbv;
    }
}

// ---------------- 4. sampling offsets / aw / loc (4 rows/block, 600 blocks) ------
__global__ __launch_bounds__(256) void samp_params_kernel(
    const float* __restrict__ x1, const float* __restrict__ qp,
    const float* __restrict__ so_w, const float* __restrict__ so_b,
    const float* __restrict__ aw_w, const float* __restrict__ aw_b,
    const float* __restrict__ refp,
    float* __restrict__ loc_out, float* __restrict__ aw_out)
{
    __shared__ float qrow[4][D_];
    __shared__ float logits[4][128];
    const int t = threadIdx.x, m0 = blockIdx.x * 4;
    for (int r = 0; r < 4; ++r)
        qrow[r][t] = x1[(m0+r)*D_ + t] + qp[(m0+r)*D_ + t];
    __syncthreads();
    {   // offsets -> loc
        float acc[4] = {0,0,0,0};
        const float4* w4 = (const float4*)(so_w + t*D_);
        for (int c = 0; c < 64; ++c) {
            float4 wv = w4[c];
#pragma unroll
            for (int r = 0; r < 4; ++r) DOT4(acc[r], wv, &qrow[r][c*4]);
        }
        const float ob = so_b[t];
        const int c_ = t & 1, l_ = (t >> 3) & 3;
        float nrm;
        if (c_ == 0) nrm = (l_==0)?152.f:(l_==1)?76.f:(l_==2)?38.f:19.f;
        else         nrm = (l_==0)?100.f:(l_==1)?50.f:(l_==2)?25.f:13.f;
        for (int r = 0; r < 4; ++r) {
            int m = m0 + r;
            float off = acc[r] + ob;
            loc_out[m*256 + t] = refp[(m*NL_ + l_)*2 + c_] + off / nrm;
        }
    }
    if (t < 128) {  // attention-weight logits
        float acc[4] = {0,0,0,0};
        const float4* w4 = (const float4*)(aw_w + t*D_);
        for (int c = 0; c < 64; ++c) {
            float4 wv = w4[c];
#pragma unroll
            for (int r = 0; r < 4; ++r) DOT4(acc[r], wv, &qrow[r][c*4]);
        }
        const float ab = aw_b[t];
        for (int r = 0; r < 4; ++r) logits[r][t] = acc[r] + ab;
    }
    __syncthreads();
    if (t < 128) {  // softmax over the 16 (l,p) per head
        const int g0 = (t >> 4) << 4;
        for (int r = 0; r < 4; ++r) {
            float mx = -1e30f;
            for (int j = 0; j < 16; ++j) mx = fmaxf(mx, logits[r][g0+j]);
            float s = 0.f;
            for (int j = 0; j < 16; ++j) s += __expf(logits[r][g0+j] - mx);
            aw_out[(m0+r)*128 + t] = __expf(logits[r][t] - mx) / s;
        }
    }
}

// ---------------- 5. deformable sampling gather (bf16), svec -> global ----------
// R5-proven: 1 query/block, channel-pair per thread, unrolled, no staging arrays.
__global__ __launch_bounds__(256) void samp_fuse_bf16_kernel(
    const unsigned short* __restrict__ vbf,
    const float* __restrict__ loc_f, const float* __restrict__ aw_f,
    float* __restrict__ svec_g, float* __restrict__ wsum_g)
{
    __shared__ int   cidx[128][4];      // clamped corner row index
    __shared__ float cwt[128][4];       // aw * bilinear weight (0 if invalid)
    const int m = blockIdx.x, t = threadIdx.x;
    const int b = m / LQ_;

    if (t < 128) {   // t = h*16 + l*4 + p
        const int l = (t >> 2) & 3;
        const int HS[4] = {100,50,25,13}, WS[4] = {152,76,38,19}, S0[4] = {0,15200,19000,19950};
        const int Hh = HS[l], Ww = WS[l], s0 = S0[l];
        const float aw = aw_f[m*128 + t];
        const float x = loc_f[m*256 + 2*t]*Ww - 0.5f;
        const float y = loc_f[m*256 + 2*t + 1]*Hh - 0.5f;
        const float x0f = floorf(x), y0f = floorf(y);
        const int x0 = (int)x0f, y0 = (int)y0f;
        const float fx = x - x0f, fy = y - y0f;
        const int   cx[4] = {x0, x0+1, x0,   x0+1};
        const int   cy[4] = {y0, y0,   y0+1, y0+1};
        const float cw[4] = {(1.f-fx)*(1.f-fy), fx*(1.f-fy), (1.f-fx)*fy, fx*fy};
        float sw = 0.f;
#pragma unroll
        for (int j = 0; j < 4; ++j) {
            const bool valid = (cx[j] >= 0) & (cx[j] < Ww) & (cy[j] >= 0) & (cy[j] < Hh);
            cidx[t][j] = valid ? (s0 + cy[j]*Ww + cx[j]) : s0;   // clamped, weight 0
            float wv = valid ? aw*cw[j] : 0.f;
            cwt[t][j] = wv;
            sw += wv;
        }
#pragma unroll
        for (int off = 8; off; off >>= 1) sw += __shfl_xor(sw, off);
        if ((t & 15) == 0) wsum_g[m*NH_ + (t >> 4)] = sw;
    }
    __syncthreads();

    // gather: thread owns channel pair (2c,2c+1), handles 4 heads (hh..hh+3)
    const int hh = (t >> 7) * 4;      // 0 or 4
    const int c  = t & 127;
    const unsigned int* sb = (const unsigned int*)(vbf + (size_t)b*LV_*D_) + c;
#pragma unroll
    for (int h = hh; h < hh + 4; ++h) {
        float e0=0.f, e1=0.f, e2=0.f, e3=0.f;   // even channel, per corner
        float o0=0.f, o1=0.f, o2=0.f, o3=0.f;   // odd channel, per corner
#pragma unroll 4
        for (int s = 0; s < 16; ++s) {
            const int base = h*16 + s;
            const int   i0 = cidx[base][0], i1 = cidx[base][1],
                        i2 = cidx[base][2], i3 = cidx[base][3];
            const float w0 = cwt[base][0], w1 = cwt[base][1],
                        w2 = cwt[base][2], w3 = cwt[base][3];
            const unsigned int u0 = sb[(size_t)i0*128];
            const unsigned int u1 = sb[(size_t)i1*128];
            const unsigned int u2 = sb[(size_t)i2*128];
            const unsigned int u3 = sb[(size_t)i3*128];
            e0 += w0*lo2f(u0); o0 += w0*hi2f(u0);
            e1 += w1*lo2f(u1); o1 += w1*hi2f(u1);
            e2 += w2*lo2f(u2); o2 += w2*hi2f(u2);
            e3 += w3*lo2f(u3); o3 += w3*hi2f(u3);
        }
        *(float2*)&svec_g[(size_t)m*(NH_*D_) + h*D_ + 2*c] =
            make_float2((e0+e1)+(e2+e3), (o0+o1)+(o2+o3));
    }
}

// ---------------- 5c. per-head value projection: vo = Wv_h @ svec_h + b*wsum ----
__global__ __launch_bounds__(256) void vproj_kernel(
    const float* __restrict__ svec_g, const float* __restrict__ wsum_g,
    const unsigned short* __restrict__ wbf, const float* __restrict__ vpb,
    float* __restrict__ vo)
{
    __shared__ float sv[4][NH_*D_];    // 32 KB
    const int t = threadIdx.x, m0 = blockIdx.x * 4;
    for (int i = t; i < 4*NH_*D_; i += 256)
        sv[i >> 11][i & 2047] = svec_g[(size_t)m0*(NH_*D_) + i];
    __syncthreads();
    const int h = t >> 5;
    const ushort4* w4 = (const ushort4*)(wbf + t*D_);
    float a0 = 0.f, a1 = 0.f, a2 = 0.f, a3 = 0.f;
    for (int c = 0; c < 64; ++c) {
        const ushort4 wq = w4[c];
        const float wx = u2f(wq.x), wy = u2f(wq.y), wz = u2f(wq.z), ww = u2f(wq.w);
        const float4 s0 = *(const float4*)&sv[0][h*D_ + c*4];
        const float4 s1 = *(const float4*)&sv[1][h*D_ + c*4];
        const float4 s2 = *(const float4*)&sv[2][h*D_ + c*4];
        const float4 s3 = *(const float4*)&sv[3][h*D_ + c*4];
        a0 += wx*s0.x + wy*s0.y + wz*s0.z + ww*s0.w;
        a1 += wx*s1.x + wy*s1.y + wz*s1.z + ww*s1.w;
        a2 += wx*s2.x + wy*s2.y + wz*s2.z + ww*s2.w;
        a3 += wx*s3.x + wy*s3.y + wz*s3.z + ww*s3.w;
    }
    const float bb = vpb[t];
    vo[(size_t)(m0+0)*D_ + t] = a0 + bb*wsum_g[(m0+0)*NH_ + h];
    vo[(size_t)(m0+1)*D_ + t] = a1 + bb*wsum_g[(m0+1)*NH_ + h];
    vo[(size_t)(m0+2)*D_ + t] = a2 + bb*wsum_g[(m0+2)*NH_ + h];
    vo[(size_t)(m0+3)*D_ + t] = a3 + bb*wsum_g[(m0+3)*NH_ + h];
}

// ---------------- 5b. fallback fp32 samp_fuse (if workspace too small) ----------
__global__ __launch_bounds__(256) void samp_fuse_f32_kernel(
    const float* __restrict__ src, const float* __restrict__ Wv,
    const float* __restrict__ vpb,
    const float* __restrict__ loc_f, const float* __restrict__ aw_f,
    float* __restrict__ vo)
{
    __shared__ float svec[NH_][D_];
    __shared__ int   cidx[128][4];
    __shared__ float cwt[128][4];
    __shared__ float wsum[NH_];
    const int m = blockIdx.x, t = threadIdx.x;
    const int b = m / LQ_;

    if (t < 128) {
        const int l = (t >> 2) & 3;
        const int HS[4] = {100,50,25,13}, WS[4] = {152,76,38,19}, S0[4] = {0,15200,19000,19950};
        const int Hh = HS[l], Ww = WS[l], s0 = S0[l];
        const float aw = aw_f[m*128 + t];
        const float x = loc_f[m*256 + 2*t]*Ww - 0.5f;
        const float y = loc_f[m*256 + 2*t + 1]*Hh - 0.5f;
        const float x0f = floorf(x), y0f = floorf(y);
        const int x0 = (int)x0f, y0 = (int)y0f;
        const float fx = x - x0f, fy = y - y0f;
        const int   cx[4] = {x0, x0+1, x0,   x0+1};
        const int   cy[4] = {y0, y0,   y0+1, y0+1};
        const float cw[4] = {(1.f-fx)*(1.f-fy), fx*(1.f-fy), (1.f-fx)*fy, fx*fy};
        float sw = 0.f;
#pragma unroll
        for (int jj = 0; jj < 4; ++jj) {
            const bool valid = (cx[jj] >= 0) & (cx[jj] < Ww) & (cy[jj] >= 0) & (cy[jj] < Hh);
            cidx[t][jj] = valid ? (s0 + cy[jj]*Ww + cx[jj]) : s0;
            float wv = valid ? aw*cw[jj] : 0.f;
            cwt[t][jj] = wv;
            sw += wv;
        }
#pragma unroll
        for (int off = 8; off; off >>= 1) sw += __shfl_xor(sw, off);
        if ((t & 15) == 0) wsum[t >> 4] = sw;
    }
    __syncthreads();

    const float* sb = src + (size_t)b*LV_*D_ + t;
#pragma unroll
    for (int h = 0; h < NH_; ++h) {
        float a0 = 0.f, a1 = 0.f, a2 = 0.f, a3 = 0.f;
#pragma unroll 4
        for (int s = 0; s < 16; ++s) {
            const int base = h*16 + s;
            const int   i0 = cidx[base][0], i1 = cidx[base][1],
                        i2 = cidx[base][2], i3 = cidx[base][3];
            const float w0 = cwt[base][0], w1 = cwt[base][1],
                        w2 = cwt[base][2], w3 = cwt[base][3];
            a0 += w0 * sb[(size_t)i0*D_];
            a1 += w1 * sb[(size_t)i1*D_];
            a2 += w2 * sb[(size_t)i2*D_];
            a3 += w3 * sb[(size_t)i3*D_];
        }
        svec[h][t] = (a0 + a1) + (a2 + a3);
    }
    __syncthreads();

    const int h = t >> 5;
    const float4* w4 = (const float4*)(Wv + t*D_);
    float a = 0.f;
    for (int c = 0; c < 64; ++c) {
        float4 wv = w4[c];
        DOT4(a, wv, &svec[h][c*4]);
    }
    vo[m*D_ + t] = a + vpb[t]*wsum[h];
}

// ---------------- 7. FFN layer 1 (relu), cc = blockIdx.y ----------------
__global__ __launch_bounds__(256) void ffn1_kernel(
    const float* __restrict__ x2, const float* __restrict__ W1,
    const float* __restrict__ b1, float* __restrict__ hid)
{
    __shared__ float arow[8][D_];
    const int t = threadIdx.x, m0 = blockIdx.x * 8, cc = blockIdx.y;
    for (int r = 0; r < 8; ++r) arow[r][t] = x2[(m0+r)*D_ + t];
    __syncthreads();
    const int j = cc*256 + t;
    float acc[8] = {0,0,0,0,0,0,0,0};
    const float4* w4 = (const float4*)(W1 + j*D_);
    for (int c = 0; c < 64; ++c) {
        float4 wv = w4[c];
#pragma unroll
        for (int r = 0; r < 8; ++r) DOT4(acc[r], wv, &arow[r][c*4]);
    }
    const float bb = b1[j];
    for (int r = 0; r < 8; ++r) {
        float v = acc[r] + bb;
        hid[(m0+r)*DFF_ + j] = v > 0.f ? v : 0.f;
    }
}

// ---------------- 8. FFN layer 2 + residual + LN (4 rows/block, 600 blocks) ------
__global__ __launch_bounds__(256) void ffn2_ln_kernel(
    const float* __restrict__ hid, const float* __restrict__ W2,
    const float* __restrict__ b2, const float* __restrict__ res,
    const float* __restrict__ gw, const float* __restrict__ gb,
    float* __restrict__ out)
{
    __shared__ float hrow[4][DFF_];    // 16 KB
    __shared__ float2 part[4][4];
    const int t = threadIdx.x, m0 = blockIdx.x * 4;
    const int w = t >> 6, lane = t & 63;
    for (int i = t; i < 4*DFF_; i += 256)
        hrow[i >> 10][i & 1023] = hid[(m0 + (i >> 10))*DFF_ + (i & 1023)];
    __syncthreads();
    float acc[4] = {0,0,0,0};
    const float4* w4 = (const float4*)(W2 + t*DFF_);
    for (int c = 0; c < 256; ++c) {
        float4 wv = w4[c];
#pragma unroll
        for (int r = 0; r < 4; ++r) DOT4(acc[r], wv, &hrow[r][c*4]);
    }
    const float bb = b2[t], gwv = gw[t], gbv = gb[t];
    float v[4];
#pragma unroll
    for (int r = 0; r < 4; ++r) {
        v[r] = acc[r] + bb + res[(m0+r)*D_+t];
        float s = v[r], ss = v[r]*v[r];
#pragma unroll
        for (int off = 32; off; off >>= 1) {
            s += __shfl_xor(s, off); ss += __shfl_xor(ss, off);
        }
        if (lane == 0) part[w][r] = make_float2(s, ss);
    }
    __syncthreads();
#pragma unroll
    for (int r = 0; r < 4; ++r) {
        float2 p0 = part[0][r], p1 = part[1][r], p2 = part[2][r], p3 = part[3][r];
        float mean = (p0.x+p1.x+p2.x+p3.x) * (1.0f/256.0f);
        float ex2  = (p0.y+p1.y+p2.y+p3.y) * (1.0f/256.0f);
        float var  = ex2 - mean*mean;
        out[(m0+r)*D_+t] = (v[r]-mean) * rsqrtf(var + 1e-5f) * gwv + gbv;
    }
}

extern "C" void kernel_launch(void* const* d_in, const int* in_sizes, int n_in,
                              void* d_out, int out_size, void* d_ws, size_t ws_size,
                              hipStream_t stream) {
    (void)in_sizes; (void)n_in; (void)out_size;
    const float* tgt  = (const float*)d_in[0];
    const float* qpos = (const float*)d_in[1];
    const float* refp = (const float*)d_in[2];
    const float* srcp = (const float*)d_in[3];
    const float* ipw  = (const float*)d_in[4];
    const float* ipb  = (const float*)d_in[5];
    const float* opw  = (const float*)d_in[6];
    const float* opb  = (const float*)d_in[7];
    const float* sow  = (const float*)d_in[8];
    const float* sob  = (const float*)d_in[9];
    const float* aww  = (const float*)d_in[10];
    const float* awb  = (const float*)d_in[11];
    const float* vpw  = (const float*)d_in[12];
    const float* vpb  = (const float*)d_in[13];
    const float* outw = (const float*)d_in[14];
    const float* outb = (const float*)d_in[15];
    const float* l1w  = (const float*)d_in[16];
    const float* l1b  = (const float*)d_in[17];
    const float* l2w  = (const float*)d_in[18];
    const float* l2b  = (const float*)d_in[19];
    const float* n1w  = (const float*)d_in[20];
    const float* n1b  = (const float*)d_in[21];
    const float* n2w  = (const float*)d_in[22];
    const float* n2b  = (const float*)d_in[23];
    const float* n3w  = (const float*)d_in[24];
    const float* n3b  = (const float*)d_in[25];

    float* wsf = (float*)d_ws;
    float* qh   = wsf;
    float* kh   = wsf + 614400;
    float* vh   = wsf + 1228800;
    float* sa   = wsf + 1843200;
    float* x1   = wsf + 2457600;
    float* vo   = wsf + 3072000;
    float* x2   = wsf + 3686400;
    float* hid  = wsf + 4300800;                       // ..6758400 floats
    unsigned short* vbf = (unsigned short*)(wsf + 6758400);            // 41,363,456 u16
    unsigned short* wbf = (unsigned short*)(wsf + 6758400 + 20681728); // 65,536 u16
    float* svec_g = wsf + 6758400 + 20681728 + 32768;  // 4,915,200 floats
    float* wsum_g = svec_g + 4915200;                  // 19,200 floats
    const size_t need_bytes = (size_t)(6758400 + 20681728 + 32768 + 4915200 + 19200) * 4;
    const bool use_bf16 = ws_size >= need_bytes;

    float* xout   = (float*)d_out;            // x   (8,300,256)
    float* locout = xout + 614400;            // loc (8,300,8,4,4,2)
    float* awout  = xout + 1228800;           // aw  (8,300,8,4,4)

    if (use_bf16)
        cvt_bf16_kernel<<<2048, 256, 0, stream>>>(srcp, vpw, vbf, wbf);
    qkv_kernel<<<dim3(NQ_/8, 3), 256, 0, stream>>>(tgt, qpos, ipw, ipb, qh, kh, vh);
    attn_kernel<<<dim3(BS_*NH_, 5), 256, 0, stream>>>(qh, kh, vh, sa);
    proj_res_ln_kernel<<<NQ_/4, 256, 0, stream>>>(sa, opw, opb, tgt, n2w, n2b, x1);
    samp_params_kernel<<<NQ_/4, 256, 0, stream>>>(x1, qpos, sow, sob, aww, awb, refp,
                                                  locout, awout);
    if (use_bf16) {
        samp_fuse_bf16_kernel<<<NQ_, 256, 0, stream>>>(vbf, locout, awout, svec_g, wsum_g);
        vproj_kernel<<<NQ_/4, 256, 0, stream>>>(svec_g, wsum_g, wbf, vpb, vo);
    } else {
        samp_fuse_f32_kernel<<<NQ_, 256, 0, stream>>>(srcp, vpw, vpb, locout, awout, vo);
    }
    proj_res_ln_kernel<<<NQ_/4, 256, 0, stream>>>(vo, outw, outb, x1, n1w, n1b, x2);
    ffn1_kernel<<<dim3(NQ_/8, 4), 256, 0, stream>>>(x2, l1w, l1b, hid);
    ffn2_ln_kernel<<<NQ_/4, 256, 0, stream>>>(hid, l2w, l2b, x2, n3w, n3b, xout);
}

// Round 8
// 673.679 us; speedup vs baseline: 1.1979x; 1.0234x over previous
//
#include <hip/hip_runtime.h>
#include <hip/hip_bf16.h>

#define D_ 256
#define NH_ 8
#define HD_ 32
#define NL_ 4
#define NP_ 4
#define DFF_ 1024
#define BS_ 8
#define LQ_ 300
#define LV_ 20197
#define NQ_ (BS_*LQ_)          // 2400
#define NSRC_ (BS_*LV_*D_)     // 41,363,456 floats

__device__ __forceinline__ float u2f(unsigned int u) {
    union { unsigned int i; float f; } v; v.i = u << 16; return v.f;
}
__device__ __forceinline__ float lo2f(unsigned int u) {
    union { unsigned int i; float f; } v; v.i = u << 16; return v.f;
}
__device__ __forceinline__ float hi2f(unsigned int u) {
    union { unsigned int i; float f; } v; v.i = u & 0xffff0000u; return v.f;
}
__device__ __forceinline__ unsigned short f2bf_bits(float f) {
    __hip_bfloat16 b = __float2bfloat16(f);
    union { __hip_bfloat16 b; unsigned short u; } v; v.b = b; return v.u;
}

// acc += dot(w4, a4)
#define DOT4(accum, wv, ap) do { \
    float4 _a = *(const float4*)(ap); \
    accum += wv.x*_a.x + wv.y*_a.y + wv.z*_a.z + wv.w*_a.w; } while(0)

// ---------------- 0a. fp32 -> bf16 conversion of src ----------------
__global__ __launch_bounds__(256) void cvt_bf16_kernel(
    const float* __restrict__ src, unsigned short* __restrict__ vbf)
{
    const int nsrc4 = NSRC_/4;
    for (int i = blockIdx.x*256 + threadIdx.x; i < nsrc4; i += gridDim.x*256) {
        float4 v = ((const float4*)src)[i];
        ushort4 o;
        o.x = f2bf_bits(v.x); o.y = f2bf_bits(v.y);
        o.z = f2bf_bits(v.z); o.w = f2bf_bits(v.w);
        ((ushort4*)vbf)[i] = o;
    }
}

// ---------------- 0b. weight packing: WP[c4][j] = float4(W[j][4c4..]) ----------
// float4-granularity transpose of 8 weight matrices; coalesced weight loads in
// all GEMV kernels (lane stride 16B instead of 1KB -> 8x fewer transactions).
__global__ __launch_bounds__(256) void pack_weights_kernel(
    const float4* __restrict__ ipw,  const float4* __restrict__ opw,
    const float4* __restrict__ sow,  const float4* __restrict__ aww,
    const float4* __restrict__ outw, const float4* __restrict__ l1w,
    const float4* __restrict__ l2w,  const float4* __restrict__ vpw,
    float4* __restrict__ ipwP,  float4* __restrict__ opwP,
    float4* __restrict__ sowP,  float4* __restrict__ awwP,
    float4* __restrict__ outwP, float4* __restrict__ l1wP,
    float4* __restrict__ l2wP,  float4* __restrict__ vpwP)
{
    __shared__ float4 tile[32][33];
    const int RS[8]  = {768,256,256,128,256,1024,256,256};
    const int C4S[8] = {64, 64, 64, 64, 64, 64, 256, 64};
    const int TCUM[9] = {0,48,64,80,88,104,168,232,248};
    int tb = blockIdx.x, mi = 0;
    while (tb >= TCUM[mi+1]) ++mi;
    const int lt = tb - TCUM[mi];
    const float4* in  = (mi==0)?ipw :(mi==1)?opw :(mi==2)?sow :(mi==3)?aww
                       :(mi==4)?outw:(mi==5)?l1w :(mi==6)?l2w :vpw;
    float4* out       = (mi==0)?ipwP:(mi==1)?opwP:(mi==2)?sowP:(mi==3)?awwP
                       :(mi==4)?outwP:(mi==5)?l1wP:(mi==6)?l2wP:vpwP;
    const int R = RS[mi], C4 = C4S[mi];
    const int tpr = C4 >> 5;
    const int by = lt / tpr, bx = lt % tpr;
    const int tx = threadIdx.x & 31, ty = threadIdx.x >> 5;
#pragma unroll
    for (int i = 0; i < 32; i += 8)
        tile[ty+i][tx] = in[(size_t)(by*32+ty+i)*C4 + bx*32+tx];
    __syncthreads();
#pragma unroll
    for (int i = 0; i < 32; i += 8)
        out[(size_t)(bx*32+ty+i)*R + by*32+tx] = tile[tx][ty+i];
}

// ---------------- 1. QKV projection (packed weights), pass = blockIdx.y ----
__global__ __launch_bounds__(256) void qkv_kernel(
    const float* __restrict__ tgt, const float* __restrict__ qp,
    const float4* __restrict__ ipwP, const float* __restrict__ bias,
    float* __restrict__ qh, float* __restrict__ kh, float* __restrict__ vh)
{
    __shared__ float arow[8][D_];
    const int t = threadIdx.x, m0 = blockIdx.x * 8, pass = blockIdx.y;
    for (int r = 0; r < 8; ++r) {
        float tv = tgt[(m0+r)*D_ + t];
        arow[r][t] = (pass == 2) ? tv : tv + qp[(m0+r)*D_ + t];
    }
    __syncthreads();
    const float4* w4 = ipwP + pass*256 + t;
    float acc[8] = {0,0,0,0,0,0,0,0};
    for (int c = 0; c < 64; ++c) {
        float4 wv = w4[c*768];
#pragma unroll
        for (int r = 0; r < 8; ++r) DOT4(acc[r], wv, &arow[r][c*4]);
    }
    float bb = bias[pass*256 + t];
    float* dst = (pass == 0) ? qh : (pass == 1) ? kh : vh;
    for (int r = 0; r < 8; ++r) dst[(m0+r)*D_ + t] = acc[r] + bb;
}

// ---------------- 2. Self attention (no inner barriers; grid.y=5) ----------------
__global__ __launch_bounds__(256) void attn_kernel(
    const float* __restrict__ qh, const float* __restrict__ kh,
    const float* __restrict__ vh, float* __restrict__ sa)
{
    __shared__ unsigned short khl[LQ_][HD_+2];
    __shared__ unsigned short vhl[LQ_][HD_+2];
    __shared__ float sc[4][LQ_];
    __shared__ float qbuf[4][HD_];
    const int b = blockIdx.x >> 3, h = blockIdx.x & 7, chunk = blockIdx.y;
    const int t = threadIdx.x, w = t >> 6, lane = t & 63;
    for (int i = t; i < LQ_*HD_; i += 256) {
        int kq = i >> 5, d = i & 31;
        khl[kq][d] = f2bf_bits(kh[(b*LQ_ + kq)*D_ + h*HD_ + d]);
        vhl[kq][d] = f2bf_bits(vh[(b*LQ_ + kq)*D_ + h*HD_ + d]);
    }
    __syncthreads();
    const float scale = 0.17677669529663687f;  // 1/sqrt(32)
    for (int qi = 0; qi < 15; ++qi) {
        const int q = chunk*60 + w*15 + qi;
        if (lane < HD_) qbuf[w][lane] = qh[(b*LQ_ + q)*D_ + h*HD_ + lane];
        float qv[HD_];
#pragma unroll
        for (int d2 = 0; d2 < HD_; ++d2) qv[d2] = qbuf[w][d2];
        float mx = -1e30f;
        for (int k = lane; k < LQ_; k += 64) {
            float s = 0.f;
#pragma unroll
            for (int d2 = 0; d2 < HD_; ++d2) s += qv[d2]*u2f(khl[k][d2]);
            s *= scale;
            sc[w][k] = s;
            mx = fmaxf(mx, s);
        }
#pragma unroll
        for (int off = 32; off; off >>= 1) mx = fmaxf(mx, __shfl_xor(mx, off));
        float lsum = 0.f;
        for (int k = lane; k < LQ_; k += 64) {
            float e = __expf(sc[w][k] - mx);
            sc[w][k] = e; lsum += e;
        }
#pragma unroll
        for (int off = 32; off; off >>= 1) lsum += __shfl_xor(lsum, off);
        const int d = lane & 31, half = lane >> 5;
        float acc = 0.f;
        for (int k = half*150; k < half*150 + 150; ++k) acc += sc[w][k]*u2f(vhl[k][d]);
        acc += __shfl_down(acc, 32);
        if (lane < 32) sa[(b*LQ_ + q)*D_ + h*HD_ + d] = acc / lsum;
    }
}

// ---------------- 3/6. proj + residual + LayerNorm (packed W, 1-barrier LN) ------
__global__ __launch_bounds__(256) void proj_res_ln_kernel(
    const float* __restrict__ A, const float4* __restrict__ WP,
    const float* __restrict__ bias, const float* __restrict__ res,
    const float* __restrict__ gw, const float* __restrict__ gb,
    float* __restrict__ out)
{
    __shared__ float arow[8][D_];
    __shared__ float2 part[4][8];
    const int t = threadIdx.x, m0 = blockIdx.x * 8;
    const int w = t >> 6, lane = t & 63;
    for (int r = 0; r < 8; ++r) arow[r][t] = A[(m0+r)*D_ + t];
    __syncthreads();
    float acc[8] = {0,0,0,0,0,0,0,0};
    const float4* w4 = WP + t;
    for (int c = 0; c < 64; ++c) {
        float4 wv = w4[c*256];
#pragma unroll
        for (int r = 0; r < 8; ++r) DOT4(acc[r], wv, &arow[r][c*4]);
    }
    const float bb = bias[t], gwv = gw[t], gbv = gb[t];
    float v[8];
#pragma unroll
    for (int r = 0; r < 8; ++r) {
        v[r] = acc[r] + bb + res[(m0+r)*D_+t];
        float s = v[r], ss = v[r]*v[r];
#pragma unroll
        for (int off = 32; off; off >>= 1) {
            s += __shfl_xor(s, off); ss += __shfl_xor(ss, off);
        }
        if (lane == 0) part[w][r] = make_float2(s, ss);
    }
    __syncthreads();
#pragma unroll
    for (int r = 0; r < 8; ++r) {
        float2 p0 = part[0][r], p1 = part[1][r], p2 = part[2][r], p3 = part[3][r];
        float mean = (p0.x+p1.x+p2.x+p3.x) * (1.0f/256.0f);
        float ex2  = (p0.y+p1.y+p2.y+p3.y) * (1.0f/256.0f);
        float var  = ex2 - mean*mean;
        out[(m0+r)*D_+t] = (v[r]-mean) * rsqrtf(var + 1e-5f) * gwv + gbv;
    }
}

// ---------------- 4. sampling offsets / aw / loc (packed weights) ----------------
__global__ __launch_bounds__(256) void samp_params_kernel(
    const float* __restrict__ x1, const float* __restrict__ qp,
    const float4* __restrict__ sowP, const float* __restrict__ so_b,
    const float4* __restrict__ awwP, const float* __restrict__ aw_b,
    const float* __restrict__ refp,
    float* __restrict__ loc_out, float* __restrict__ aw_out)
{
    __shared__ float qrow[8][D_];
    __shared__ float logits[8][128];
    const int t = threadIdx.x, m0 = blockIdx.x * 8;
    for (int r = 0; r < 8; ++r)
        qrow[r][t] = x1[(m0+r)*D_ + t] + qp[(m0+r)*D_ + t];
    __syncthreads();
    {   // offsets -> loc
        float acc[8] = {0,0,0,0,0,0,0,0};
        const float4* w4 = sowP + t;
        for (int c = 0; c < 64; ++c) {
            float4 wv = w4[c*256];
#pragma unroll
            for (int r = 0; r < 8; ++r) DOT4(acc[r], wv, &qrow[r][c*4]);
        }
        const float ob = so_b[t];
        const int c_ = t & 1, l_ = (t >> 3) & 3;
        float nrm;
        if (c_ == 0) nrm = (l_==0)?152.f:(l_==1)?76.f:(l_==2)?38.f:19.f;
        else         nrm = (l_==0)?100.f:(l_==1)?50.f:(l_==2)?25.f:13.f;
        for (int r = 0; r < 8; ++r) {
            int m = m0 + r;
            float off = acc[r] + ob;
            loc_out[m*256 + t] = refp[(m*NL_ + l_)*2 + c_] + off / nrm;
        }
    }
    if (t < 128) {  // attention-weight logits
        float acc[8] = {0,0,0,0,0,0,0,0};
        const float4* w4 = awwP + t;
        for (int c = 0; c < 64; ++c) {
            float4 wv = w4[c*128];
#pragma unroll
            for (int r = 0; r < 8; ++r) DOT4(acc[r], wv, &qrow[r][c*4]);
        }
        const float ab = aw_b[t];
        for (int r = 0; r < 8; ++r) logits[r][t] = acc[r] + ab;
    }
    __syncthreads();
    if (t < 128) {  // softmax over the 16 (l,p) per head
        const int g0 = (t >> 4) << 4;
        for (int r = 0; r < 8; ++r) {
            float mx = -1e30f;
            for (int j = 0; j < 16; ++j) mx = fmaxf(mx, logits[r][g0+j]);
            float s = 0.f;
            for (int j = 0; j < 16; ++j) s += __expf(logits[r][g0+j] - mx);
            aw_out[(m0+r)*128 + t] = __expf(logits[r][t] - mx) / s;
        }
    }
}

// ---------------- 5. deformable sampling gather (bf16), R5-proven ----------------
__global__ __launch_bounds__(256) void samp_fuse_bf16_kernel(
    const unsigned short* __restrict__ vbf,
    const float* __restrict__ loc_f, const float* __restrict__ aw_f,
    float* __restrict__ svec_g, float* __restrict__ wsum_g)
{
    __shared__ int   cidx[128][4];
    __shared__ float cwt[128][4];
    const int m = blockIdx.x, t = threadIdx.x;
    const int b = m / LQ_;

    if (t < 128) {   // t = h*16 + l*4 + p
        const int l = (t >> 2) & 3;
        const int HS[4] = {100,50,25,13}, WS[4] = {152,76,38,19}, S0[4] = {0,15200,19000,19950};
        const int Hh = HS[l], Ww = WS[l], s0 = S0[l];
        const float aw = aw_f[m*128 + t];
        const float x = loc_f[m*256 + 2*t]*Ww - 0.5f;
        const float y = loc_f[m*256 + 2*t + 1]*Hh - 0.5f;
        const float x0f = floorf(x), y0f = floorf(y);
        const int x0 = (int)x0f, y0 = (int)y0f;
        const float fx = x - x0f, fy = y - y0f;
        const int   cx[4] = {x0, x0+1, x0,   x0+1};
        const int   cy[4] = {y0, y0,   y0+1, y0+1};
        const float cw[4] = {(1.f-fx)*(1.f-fy), fx*(1.f-fy), (1.f-fx)*fy, fx*fy};
        float sw = 0.f;
#pragma unroll
        for (int j = 0; j < 4; ++j) {
            const bool valid = (cx[j] >= 0) & (cx[j] < Ww) & (cy[j] >= 0) & (cy[j] < Hh);
            cidx[t][j] = valid ? (s0 + cy[j]*Ww + cx[j]) : s0;
            float wv = valid ? aw*cw[j] : 0.f;
            cwt[t][j] = wv;
            sw += wv;
        }
#pragma unroll
        for (int off = 8; off; off >>= 1) sw += __shfl_xor(sw, off);
        if ((t & 15) == 0) wsum_g[m*NH_ + (t >> 4)] = sw;
    }
    __syncthreads();

    const int hh = (t >> 7) * 4;
    const int c  = t & 127;
    const unsigned int* sb = (const unsigned int*)(vbf + (size_t)b*LV_*D_) + c;
#pragma unroll
    for (int h = hh; h < hh + 4; ++h) {
        float e0=0.f, e1=0.f, e2=0.f, e3=0.f;
        float o0=0.f, o1=0.f, o2=0.f, o3=0.f;
#pragma unroll 4
        for (int s = 0; s < 16; ++s) {
            const int base = h*16 + s;
            const int   i0 = cidx[base][0], i1 = cidx[base][1],
                        i2 = cidx[base][2], i3 = cidx[base][3];
            const float w0 = cwt[base][0], w1 = cwt[base][1],
                        w2 = cwt[base][2], w3 = cwt[base][3];
            const unsigned int u0 = sb[(size_t)i0*128];
            const unsigned int u1 = sb[(size_t)i1*128];
            const unsigned int u2 = sb[(size_t)i2*128];
            const unsigned int u3 = sb[(size_t)i3*128];
            e0 += w0*lo2f(u0); o0 += w0*hi2f(u0);
            e1 += w1*lo2f(u1); o1 += w1*hi2f(u1);
            e2 += w2*lo2f(u2); o2 += w2*hi2f(u2);
            e3 += w3*lo2f(u3); o3 += w3*hi2f(u3);
        }
        *(float2*)&svec_g[(size_t)m*(NH_*D_) + h*D_ + 2*c] =
            make_float2((e0+e1)+(e2+e3), (o0+o1)+(o2+o3));
    }
}

// ---------------- 5c. per-head value projection (packed fp32 weights) ------------
__global__ __launch_bounds__(256) void vproj_kernel(
    const float* __restrict__ svec_g, const float* __restrict__ wsum_g,
    const float4* __restrict__ vpwP, const float* __restrict__ vpb,
    float* __restrict__ vo)
{
    __shared__ float sv[4][NH_*D_];    // 32 KB
    const int t = threadIdx.x, m0 = blockIdx.x * 4;
    for (int i = t; i < 4*NH_*D_; i += 256)
        sv[i >> 11][i & 2047] = svec_g[(size_t)m0*(NH_*D_) + i];
    __syncthreads();
    const int h = t >> 5;
    const float4* w4 = vpwP + t;
    float a0 = 0.f, a1 = 0.f, a2 = 0.f, a3 = 0.f;
    for (int c = 0; c < 64; ++c) {
        const float4 wq = w4[c*256];
        const float4 s0 = *(const float4*)&sv[0][h*D_ + c*4];
        const float4 s1 = *(const float4*)&sv[1][h*D_ + c*4];
        const float4 s2 = *(const float4*)&sv[2][h*D_ + c*4];
        const float4 s3 = *(const float4*)&sv[3][h*D_ + c*4];
        a0 += wq.x*s0.x + wq.y*s0.y + wq.z*s0.z + wq.w*s0.w;
        a1 += wq.x*s1.x + wq.y*s1.y + wq.z*s1.z + wq.w*s1.w;
        a2 += wq.x*s2.x + wq.y*s2.y + wq.z*s2.z + wq.w*s2.w;
        a3 += wq.x*s3.x + wq.y*s3.y + wq.z*s3.z + wq.w*s3.w;
    }
    const float bb = vpb[t];
    vo[(size_t)(m0+0)*D_ + t] = a0 + bb*wsum_g[(m0+0)*NH_ + h];
    vo[(size_t)(m0+1)*D_ + t] = a1 + bb*wsum_g[(m0+1)*NH_ + h];
    vo[(size_t)(m0+2)*D_ + t] = a2 + bb*wsum_g[(m0+2)*NH_ + h];
    vo[(size_t)(m0+3)*D_ + t] = a3 + bb*wsum_g[(m0+3)*NH_ + h];
}

// ---------------- 5b. fallback fp32 samp_fuse (if workspace too small) ----------
__global__ __launch_bounds__(256) void samp_fuse_f32_kernel(
    const float* __restrict__ src, const float* __restrict__ Wv,
    const float* __restrict__ vpb,
    const float* __restrict__ loc_f, const float* __restrict__ aw_f,
    float* __restrict__ vo)
{
    __shared__ float svec[NH_][D_];
    __shared__ int   cidx[128][4];
    __shared__ float cwt[128][4];
    __shared__ float wsum[NH_];
    const int m = blockIdx.x, t = threadIdx.x;
    const int b = m / LQ_;

    if (t < 128) {
        const int l = (t >> 2) & 3;
        const int HS[4] = {100,50,25,13}, WS[4] = {152,76,38,19}, S0[4] = {0,15200,19000,19950};
        const int Hh = HS[l], Ww = WS[l], s0 = S0[l];
        const float aw = aw_f[m*128 + t];
        const float x = loc_f[m*256 + 2*t]*Ww - 0.5f;
        const float y = loc_f[m*256 + 2*t + 1]*Hh - 0.5f;
        const float x0f = floorf(x), y0f = floorf(y);
        const int x0 = (int)x0f, y0 = (int)y0f;
        const float fx = x - x0f, fy = y - y0f;
        const int   cx[4] = {x0, x0+1, x0,   x0+1};
        const int   cy[4] = {y0, y0,   y0+1, y0+1};
        const float cw[4] = {(1.f-fx)*(1.f-fy), fx*(1.f-fy), (1.f-fx)*fy, fx*fy};
        float sw = 0.f;
#pragma unroll
        for (int jj = 0; jj < 4; ++jj) {
            const bool valid = (cx[jj] >= 0) & (cx[jj] < Ww) & (cy[jj] >= 0) & (cy[jj] < Hh);
            cidx[t][jj] = valid ? (s0 + cy[jj]*Ww + cx[jj]) : s0;
            float wv = valid ? aw*cw[jj] : 0.f;
            cwt[t][jj] = wv;
            sw += wv;
        }
#pragma unroll
        for (int off = 8; off; off >>= 1) sw += __shfl_xor(sw, off);
        if ((t & 15) == 0) wsum[t >> 4] = sw;
    }
    __syncthreads();

    const float* sb = src + (size_t)b*LV_*D_ + t;
#pragma unroll
    for (int h = 0; h < NH_; ++h) {
        float a0 = 0.f, a1 = 0.f, a2 = 0.f, a3 = 0.f;
#pragma unroll 4
        for (int s = 0; s < 16; ++s) {
            const int base = h*16 + s;
            const int   i0 = cidx[base][0], i1 = cidx[base][1],
                        i2 = cidx[base][2], i3 = cidx[base][3];
            const float w0 = cwt[base][0], w1 = cwt[base][1],
                        w2 = cwt[base][2], w3 = cwt[base][3];
            a0 += w0 * sb[(size_t)i0*D_];
            a1 += w1 * sb[(size_t)i1*D_];
            a2 += w2 * sb[(size_t)i2*D_];
            a3 += w3 * sb[(size_t)i3*D_];
        }
        svec[h][t] = (a0 + a1) + (a2 + a3);
    }
    __syncthreads();

    const int h = t >> 5;
    const float4* w4 = (const float4*)(Wv + t*D_);
    float a = 0.f;
    for (int c = 0; c < 64; ++c) {
        float4 wv = w4[c];
        DOT4(a, wv, &svec[h][c*4]);
    }
    vo[m*D_ + t] = a + vpb[t]*wsum[h];
}

// ---------------- 7. FFN layer 1 (relu, packed weights), cc = blockIdx.y ---------
__global__ __launch_bounds__(256) void ffn1_kernel(
    const float* __restrict__ x2, const float4* __restrict__ l1wP,
    const float* __restrict__ b1, float* __restrict__ hid)
{
    __shared__ float arow[8][D_];
    const int t = threadIdx.x, m0 = blockIdx.x * 8, cc = blockIdx.y;
    for (int r = 0; r < 8; ++r) arow[r][t] = x2[(m0+r)*D_ + t];
    __syncthreads();
    const int j = cc*256 + t;
    float acc[8] = {0,0,0,0,0,0,0,0};
    const float4* w4 = l1wP + j;
    for (int c = 0; c < 64; ++c) {
        float4 wv = w4[c*1024];
#pragma unroll
        for (int r = 0; r < 8; ++r) DOT4(acc[r], wv, &arow[r][c*4]);
    }
    const float bb = b1[j];
    for (int r = 0; r < 8; ++r) {
        float v = acc[r] + bb;
        hid[(m0+r)*DFF_ + j] = v > 0.f ? v : 0.f;
    }
}

// ---------------- 8. FFN layer 2 + residual + LN (packed, 1-barrier LN) ----------
__global__ __launch_bounds__(256) void ffn2_ln_kernel(
    const float* __restrict__ hid, const float4* __restrict__ l2wP,
    const float* __restrict__ b2, const float* __restrict__ res,
    const float* __restrict__ gw, const float* __restrict__ gb,
    float* __restrict__ out)
{
    __shared__ float hrow[8][DFF_];
    __shared__ float2 part[4][8];
    const int t = threadIdx.x, m0 = blockIdx.x * 8;
    const int w = t >> 6, lane = t & 63;
    for (int i = t; i < 8*DFF_; i += 256)
        hrow[i >> 10][i & 1023] = hid[(m0 + (i >> 10))*DFF_ + (i & 1023)];
    __syncthreads();
    float acc[8] = {0,0,0,0,0,0,0,0};
    const float4* w4 = l2wP + t;
    for (int c = 0; c < 256; ++c) {
        float4 wv = w4[c*256];
#pragma unroll
        for (int r = 0; r < 8; ++r) DOT4(acc[r], wv, &hrow[r][c*4]);
    }
    const float bb = b2[t], gwv = gw[t], gbv = gb[t];
    float v[8];
#pragma unroll
    for (int r = 0; r < 8; ++r) {
        v[r] = acc[r] + bb + res[(m0+r)*D_+t];
        float s = v[r], ss = v[r]*v[r];
#pragma unroll
        for (int off = 32; off; off >>= 1) {
            s += __shfl_xor(s, off); ss += __shfl_xor(ss, off);
        }
        if (lane == 0) part[w][r] = make_float2(s, ss);
    }
    __syncthreads();
#pragma unroll
    for (int r = 0; r < 8; ++r) {
        float2 p0 = part[0][r], p1 = part[1][r], p2 = part[2][r], p3 = part[3][r];
        float mean = (p0.x+p1.x+p2.x+p3.x) * (1.0f/256.0f);
        float ex2  = (p0.y+p1.y+p2.y+p3.y) * (1.0f/256.0f);
        float var  = ex2 - mean*mean;
        out[(m0+r)*D_+t] = (v[r]-mean) * rsqrtf(var + 1e-5f) * gwv + gbv;
    }
}

extern "C" void kernel_launch(void* const* d_in, const int* in_sizes, int n_in,
                              void* d_out, int out_size, void* d_ws, size_t ws_size,
                              hipStream_t stream) {
    (void)in_sizes; (void)n_in; (void)out_size;
    const float* tgt  = (const float*)d_in[0];
    const float* qpos = (const float*)d_in[1];
    const float* refp = (const float*)d_in[2];
    const float* srcp = (const float*)d_in[3];
    const float* ipw  = (const float*)d_in[4];
    const float* ipb  = (const float*)d_in[5];
    const float* opw  = (const float*)d_in[6];
    const float* opb  = (const float*)d_in[7];
    const float* sow  = (const float*)d_in[8];
    const float* sob  = (const float*)d_in[9];
    const float* aww  = (const float*)d_in[10];
    const float* awb  = (const float*)d_in[11];
    const float* vpw  = (const float*)d_in[12];
    const float* vpb  = (const float*)d_in[13];
    const float* outw = (const float*)d_in[14];
    const float* outb = (const float*)d_in[15];
    const float* l1w  = (const float*)d_in[16];
    const float* l1b  = (const float*)d_in[17];
    const float* l2w  = (const float*)d_in[18];
    const float* l2b  = (const float*)d_in[19];
    const float* n1w  = (const float*)d_in[20];
    const float* n1b  = (const float*)d_in[21];
    const float* n2w  = (const float*)d_in[22];
    const float* n2b  = (const float*)d_in[23];
    const float* n3w  = (const float*)d_in[24];
    const float* n3b  = (const float*)d_in[25];

    float* wsf = (float*)d_ws;
    float* qh   = wsf;
    float* kh   = wsf + 614400;
    float* vh   = wsf + 1228800;
    float* sa   = wsf + 1843200;
    float* x1   = wsf + 2457600;
    float* vo   = wsf + 3072000;
    float* x2   = wsf + 3686400;
    float* hid  = wsf + 4300800;                  // ..6758400
    // packed weights (float4 views), 1,015,808 floats total
    float* P0    = wsf + 6758400;
    float4* ipwP  = (float4*)(P0);                //  768x64 f4
    float4* opwP  = (float4*)(P0 + 196608);       //  256x64
    float4* sowP  = (float4*)(P0 + 262144);       //  256x64
    float4* awwP  = (float4*)(P0 + 327680);       //  128x64
    float4* outwP = (float4*)(P0 + 360448);       //  256x64
    float4* l1wP  = (float4*)(P0 + 425984);       // 1024x64
    float4* l2wP  = (float4*)(P0 + 688128);       //  256x256
    float4* vpwP  = (float4*)(P0 + 950272);       //  256x64
    unsigned short* vbf = (unsigned short*)(wsf + 7774208);   // NSRC_ u16
    float* svec_g = wsf + 7774208 + 20681728;     // 4,915,200 floats
    float* wsum_g = svec_g + 4915200;             // 19,200 floats
    const size_t need_bytes = (size_t)(7774208 + 20681728 + 4915200 + 19200) * 4;
    const bool use_bf16 = ws_size >= need_bytes;

    float* xout   = (float*)d_out;            // x   (8,300,256)
    float* locout = xout + 614400;            // loc (8,300,8,4,4,2)
    float* awout  = xout + 1228800;           // aw  (8,300,8,4,4)

    pack_weights_kernel<<<248, 256, 0, stream>>>(
        (const float4*)ipw, (const float4*)opw, (const float4*)sow,
        (const float4*)aww, (const float4*)outw, (const float4*)l1w,
        (const float4*)l2w, (const float4*)vpw,
        ipwP, opwP, sowP, awwP, outwP, l1wP, l2wP, vpwP);
    if (use_bf16)
        cvt_bf16_kernel<<<2048, 256, 0, stream>>>(srcp, vbf);
    qkv_kernel<<<dim3(NQ_/8, 3), 256, 0, stream>>>(tgt, qpos, ipwP, ipb, qh, kh, vh);
    attn_kernel<<<dim3(BS_*NH_, 5), 256, 0, stream>>>(qh, kh, vh, sa);
    proj_res_ln_kernel<<<NQ_/8, 256, 0, stream>>>(sa, opwP, opb, tgt, n2w, n2b, x1);
    samp_params_kernel<<<NQ_/8, 256, 0, stream>>>(x1, qpos, sowP, sob, awwP, awb, refp,
                                                  locout, awout);
    if (use_bf16) {
        samp_fuse_bf16_kernel<<<NQ_, 256, 0, stream>>>(vbf, locout, awout, svec_g, wsum_g);
        vproj_kernel<<<NQ_/4, 256, 0, stream>>>(svec_g, wsum_g, vpwP, vpb, vo);
    } else {
        samp_fuse_f32_kernel<<<NQ_, 256, 0, stream>>>(srcp, vpw, vpb, locout, awout, vo);
    }
    proj_res_ln_kernel<<<NQ_/8, 256, 0, stream>>>(vo, outwP, outb, x1, n1w, n1b, x2);
    ffn1_kernel<<<dim3(NQ_/8, 4), 256, 0, stream>>>(x2, l1wP, l1b, hid);
    ffn2_ln_kernel<<<NQ_/8, 256, 0, stream>>>(hid, l2wP, l2b, x2, n3w, n3b, xout);
}

// Round 9
// 656.350 us; speedup vs baseline: 1.2295x; 1.0264x over previous
//
#include <hip/hip_runtime.h>
#include <hip/hip_bf16.h>

#define D_ 256
#define NH_ 8
#define HD_ 32
#define NL_ 4
#define NP_ 4
#define DFF_ 1024
#define BS_ 8
#define LQ_ 300
#define LV_ 20197
#define NQ_ (BS_*LQ_)          // 2400
#define NSRC_ (BS_*LV_*D_)     // 41,363,456 floats

__device__ __forceinline__ float u2f(unsigned int u) {
    union { unsigned int i; float f; } v; v.i = u << 16; return v.f;
}
__device__ __forceinline__ float lo2f(unsigned int u) {
    union { unsigned int i; float f; } v; v.i = u << 16; return v.f;
}
__device__ __forceinline__ float hi2f(unsigned int u) {
    union { unsigned int i; float f; } v; v.i = u & 0xffff0000u; return v.f;
}
__device__ __forceinline__ unsigned short f2bf_bits(float f) {
    __hip_bfloat16 b = __float2bfloat16(f);
    union { __hip_bfloat16 b; unsigned short u; } v; v.b = b; return v.u;
}

// acc += dot(w4, a4)  (ap uniform -> compiler emits s_load_dwordx4)
#define DOT4(accum, wv, ap) do { \
    float4 _a = *(const float4*)(ap); \
    accum += wv.x*_a.x + wv.y*_a.y + wv.z*_a.z + wv.w*_a.w; } while(0)

// ---------------- 0a. fp32 -> bf16 conversion of src ----------------
__global__ __launch_bounds__(256) void cvt_bf16_kernel(
    const float* __restrict__ src, unsigned short* __restrict__ vbf)
{
    const int nsrc4 = NSRC_/4;
    for (int i = blockIdx.x*256 + threadIdx.x; i < nsrc4; i += gridDim.x*256) {
        float4 v = ((const float4*)src)[i];
        ushort4 o;
        o.x = f2bf_bits(v.x); o.y = f2bf_bits(v.y);
        o.z = f2bf_bits(v.z); o.w = f2bf_bits(v.w);
        ((ushort4*)vbf)[i] = o;
    }
}

// ---------------- 0c. qk = tgt + qpos (for uniform reads in qkv) ----------------
__global__ __launch_bounds__(256) void add_qk_kernel(
    const float* __restrict__ tgt, const float* __restrict__ qp,
    float* __restrict__ qk)
{
    const int i = blockIdx.x*256 + threadIdx.x;
    float4 a = ((const float4*)tgt)[i], b = ((const float4*)qp)[i];
    ((float4*)qk)[i] = make_float4(a.x+b.x, a.y+b.y, a.z+b.z, a.w+b.w);
}

// ---------------- 0b. weight packing: WP[c4][j] = float4(W[j][4c4..]) ----------
__global__ __launch_bounds__(256) void pack_weights_kernel(
    const float4* __restrict__ ipw,  const float4* __restrict__ opw,
    const float4* __restrict__ sow,  const float4* __restrict__ aww,
    const float4* __restrict__ outw, const float4* __restrict__ l1w,
    const float4* __restrict__ l2w,  const float4* __restrict__ vpw,
    float4* __restrict__ ipwP,  float4* __restrict__ opwP,
    float4* __restrict__ sowP,  float4* __restrict__ awwP,
    float4* __restrict__ outwP, float4* __restrict__ l1wP,
    float4* __restrict__ l2wP,  float4* __restrict__ vpwP)
{
    __shared__ float4 tile[32][33];
    const int RS[8]  = {768,256,256,128,256,1024,256,256};
    const int C4S[8] = {64, 64, 64, 64, 64, 64, 256, 64};
    const int TCUM[9] = {0,48,64,80,88,104,168,232,248};
    int tb = blockIdx.x, mi = 0;
    while (tb >= TCUM[mi+1]) ++mi;
    const int lt = tb - TCUM[mi];
    const float4* in  = (mi==0)?ipw :(mi==1)?opw :(mi==2)?sow :(mi==3)?aww
                       :(mi==4)?outw:(mi==5)?l1w :(mi==6)?l2w :vpw;
    float4* out       = (mi==0)?ipwP:(mi==1)?opwP:(mi==2)?sowP:(mi==3)?awwP
                       :(mi==4)?outwP:(mi==5)?l1wP:(mi==6)?l2wP:vpwP;
    const int R = RS[mi], C4 = C4S[mi];
    const int tpr = C4 >> 5;
    const int by = lt / tpr, bx = lt % tpr;
    const int tx = threadIdx.x & 31, ty = threadIdx.x >> 5;
#pragma unroll
    for (int i = 0; i < 32; i += 8)
        tile[ty+i][tx] = in[(size_t)(by*32+ty+i)*C4 + bx*32+tx];
    __syncthreads();
#pragma unroll
    for (int i = 0; i < 32; i += 8)
        out[(size_t)(bx*32+ty+i)*R + by*32+tx] = tile[tx][ty+i];
}

// ---------------- 1. QKV projection: uniform scalar activation loads -------------
__global__ __launch_bounds__(256) void qkv_kernel(
    const float* __restrict__ qk, const float* __restrict__ tgt,
    const float4* __restrict__ ipwP, const float* __restrict__ bias,
    float* __restrict__ qh, float* __restrict__ kh, float* __restrict__ vh)
{
    const int t = threadIdx.x, m0 = blockIdx.x * 8, pass = blockIdx.y;
    const float* a0 = ((pass == 2) ? tgt : qk) + (size_t)m0*D_;
    const float4* w4 = ipwP + pass*256 + t;
    float acc[8] = {0,0,0,0,0,0,0,0};
#pragma unroll 4
    for (int c = 0; c < 64; ++c) {
        float4 wv = w4[c*768];
#pragma unroll
        for (int r = 0; r < 8; ++r) DOT4(acc[r], wv, a0 + r*D_ + c*4);
    }
    float bb = bias[pass*256 + t];
    float* dst = (pass == 0) ? qh : (pass == 1) ? kh : vh;
    for (int r = 0; r < 8; ++r) dst[(m0+r)*D_ + t] = acc[r] + bb;
}

// ---------------- 2. Self attention (no inner barriers; grid.y=5) ----------------
__global__ __launch_bounds__(256) void attn_kernel(
    const float* __restrict__ qh, const float* __restrict__ kh,
    const float* __restrict__ vh, float* __restrict__ sa)
{
    __shared__ unsigned short khl[LQ_][HD_+2];
    __shared__ unsigned short vhl[LQ_][HD_+2];
    __shared__ float sc[4][LQ_];
    __shared__ float qbuf[4][HD_];
    const int b = blockIdx.x >> 3, h = blockIdx.x & 7, chunk = blockIdx.y;
    const int t = threadIdx.x, w = t >> 6, lane = t & 63;
    for (int i = t; i < LQ_*HD_; i += 256) {
        int kq = i >> 5, d = i & 31;
        khl[kq][d] = f2bf_bits(kh[(b*LQ_ + kq)*D_ + h*HD_ + d]);
        vhl[kq][d] = f2bf_bits(vh[(b*LQ_ + kq)*D_ + h*HD_ + d]);
    }
    __syncthreads();
    const float scale = 0.17677669529663687f;  // 1/sqrt(32)
    for (int qi = 0; qi < 15; ++qi) {
        const int q = chunk*60 + w*15 + qi;
        if (lane < HD_) qbuf[w][lane] = qh[(b*LQ_ + q)*D_ + h*HD_ + lane];
        float qv[HD_];
#pragma unroll
        for (int d2 = 0; d2 < HD_; ++d2) qv[d2] = qbuf[w][d2];
        float mx = -1e30f;
        for (int k = lane; k < LQ_; k += 64) {
            float s = 0.f;
#pragma unroll
            for (int d2 = 0; d2 < HD_; ++d2) s += qv[d2]*u2f(khl[k][d2]);
            s *= scale;
            sc[w][k] = s;
            mx = fmaxf(mx, s);
        }
#pragma unroll
        for (int off = 32; off; off >>= 1) mx = fmaxf(mx, __shfl_xor(mx, off));
        float lsum = 0.f;
        for (int k = lane; k < LQ_; k += 64) {
            float e = __expf(sc[w][k] - mx);
            sc[w][k] = e; lsum += e;
        }
#pragma unroll
        for (int off = 32; off; off >>= 1) lsum += __shfl_xor(lsum, off);
        const int d = lane & 31, half = lane >> 5;
        float acc = 0.f;
        for (int k = half*150; k < half*150 + 150; ++k) acc += sc[w][k]*u2f(vhl[k][d]);
        acc += __shfl_down(acc, 32);
        if (lane < 32) sa[(b*LQ_ + q)*D_ + h*HD_ + d] = acc / lsum;
    }
}

// ---------------- 3/6. proj + residual + LN (uniform scalar A-loads) -------------
// Optional x1q output: x1q = out + qp (feeds samp_params' uniform reads).
__global__ __launch_bounds__(256) void proj_res_ln_kernel(
    const float* __restrict__ A, const float4* __restrict__ WP,
    const float* __restrict__ bias, const float* __restrict__ res,
    const float* __restrict__ gw, const float* __restrict__ gb,
    float* __restrict__ out, const float* __restrict__ qp,
    float* __restrict__ outq)
{
    __shared__ float2 part[4][8];
    const int t = threadIdx.x, m0 = blockIdx.x * 8;
    const int w = t >> 6, lane = t & 63;
    const float* a0 = A + (size_t)m0*D_;
    float acc[8] = {0,0,0,0,0,0,0,0};
    const float4* w4 = WP + t;
#pragma unroll 4
    for (int c = 0; c < 64; ++c) {
        float4 wv = w4[c*256];
#pragma unroll
        for (int r = 0; r < 8; ++r) DOT4(acc[r], wv, a0 + r*D_ + c*4);
    }
    const float bb = bias[t], gwv = gw[t], gbv = gb[t];
    float v[8];
#pragma unroll
    for (int r = 0; r < 8; ++r) {
        v[r] = acc[r] + bb + res[(m0+r)*D_+t];
        float s = v[r], ss = v[r]*v[r];
#pragma unroll
        for (int off = 32; off; off >>= 1) {
            s += __shfl_xor(s, off); ss += __shfl_xor(ss, off);
        }
        if (lane == 0) part[w][r] = make_float2(s, ss);
    }
    __syncthreads();
#pragma unroll
    for (int r = 0; r < 8; ++r) {
        float2 p0 = part[0][r], p1 = part[1][r], p2 = part[2][r], p3 = part[3][r];
        float mean = (p0.x+p1.x+p2.x+p3.x) * (1.0f/256.0f);
        float ex2  = (p0.y+p1.y+p2.y+p3.y) * (1.0f/256.0f);
        float var  = ex2 - mean*mean;
        float o = (v[r]-mean) * rsqrtf(var + 1e-5f) * gwv + gbv;
        out[(m0+r)*D_+t] = o;
        if (outq) outq[(m0+r)*D_+t] = o + qp[(m0+r)*D_+t];
    }
}

// ---------------- 4. sampling offsets / aw / loc (uniform A-loads from x1q) ------
__global__ __launch_bounds__(256) void samp_params_kernel(
    const float* __restrict__ x1q,
    const float4* __restrict__ sowP, const float* __restrict__ so_b,
    const float4* __restrict__ awwP, const float* __restrict__ aw_b,
    const float* __restrict__ refp,
    float* __restrict__ loc_out, float* __restrict__ aw_out)
{
    __shared__ float logits[8][128];
    const int t = threadIdx.x, m0 = blockIdx.x * 8;
    const float* a0 = x1q + (size_t)m0*D_;
    {   // offsets -> loc
        float acc[8] = {0,0,0,0,0,0,0,0};
        const float4* w4 = sowP + t;
#pragma unroll 4
        for (int c = 0; c < 64; ++c) {
            float4 wv = w4[c*256];
#pragma unroll
            for (int r = 0; r < 8; ++r) DOT4(acc[r], wv, a0 + r*D_ + c*4);
        }
        const float ob = so_b[t];
        const int c_ = t & 1, l_ = (t >> 3) & 3;
        float nrm;
        if (c_ == 0) nrm = (l_==0)?152.f:(l_==1)?76.f:(l_==2)?38.f:19.f;
        else         nrm = (l_==0)?100.f:(l_==1)?50.f:(l_==2)?25.f:13.f;
        for (int r = 0; r < 8; ++r) {
            int m = m0 + r;
            float off = acc[r] + ob;
            loc_out[m*256 + t] = refp[(m*NL_ + l_)*2 + c_] + off / nrm;
        }
    }
    if (t < 128) {  // attention-weight logits
        float acc[8] = {0,0,0,0,0,0,0,0};
        const float4* w4 = awwP + t;
#pragma unroll 4
        for (int c = 0; c < 64; ++c) {
            float4 wv = w4[c*128];
#pragma unroll
            for (int r = 0; r < 8; ++r) DOT4(acc[r], wv, a0 + r*D_ + c*4);
        }
        const float ab = aw_b[t];
        for (int r = 0; r < 8; ++r) logits[r][t] = acc[r] + ab;
    }
    __syncthreads();
    if (t < 128) {  // softmax over the 16 (l,p) per head
        const int g0 = (t >> 4) << 4;
        for (int r = 0; r < 8; ++r) {
            float mx = -1e30f;
            for (int j = 0; j < 16; ++j) mx = fmaxf(mx, logits[r][g0+j]);
            float s = 0.f;
            for (int j = 0; j < 16; ++j) s += __expf(logits[r][g0+j] - mx);
            aw_out[(m0+r)*128 + t] = __expf(logits[r][t] - mx) / s;
        }
    }
}

// ---------------- 5. deformable sampling gather (bf16), R5-proven ----------------
__global__ __launch_bounds__(256) void samp_fuse_bf16_kernel(
    const unsigned short* __restrict__ vbf,
    const float* __restrict__ loc_f, const float* __restrict__ aw_f,
    float* __restrict__ svec_g, float* __restrict__ wsum_g)
{
    __shared__ int   cidx[128][4];
    __shared__ float cwt[128][4];
    const int m = blockIdx.x, t = threadIdx.x;
    const int b = m / LQ_;

    if (t < 128) {   // t = h*16 + l*4 + p
        const int l = (t >> 2) & 3;
        const int HS[4] = {100,50,25,13}, WS[4] = {152,76,38,19}, S0[4] = {0,15200,19000,19950};
        const int Hh = HS[l], Ww = WS[l], s0 = S0[l];
        const float aw = aw_f[m*128 + t];
        const float x = loc_f[m*256 + 2*t]*Ww - 0.5f;
        const float y = loc_f[m*256 + 2*t + 1]*Hh - 0.5f;
        const float x0f = floorf(x), y0f = floorf(y);
        const int x0 = (int)x0f, y0 = (int)y0f;
        const float fx = x - x0f, fy = y - y0f;
        const int   cx[4] = {x0, x0+1, x0,   x0+1};
        const int   cy[4] = {y0, y0,   y0+1, y0+1};
        const float cw[4] = {(1.f-fx)*(1.f-fy), fx*(1.f-fy), (1.f-fx)*fy, fx*fy};
        float sw = 0.f;
#pragma unroll
        for (int j = 0; j < 4; ++j) {
            const bool valid = (cx[j] >= 0) & (cx[j] < Ww) & (cy[j] >= 0) & (cy[j] < Hh);
            cidx[t][j] = valid ? (s0 + cy[j]*Ww + cx[j]) : s0;
            float wv = valid ? aw*cw[j] : 0.f;
            cwt[t][j] = wv;
            sw += wv;
        }
#pragma unroll
        for (int off = 8; off; off >>= 1) sw += __shfl_xor(sw, off);
        if ((t & 15) == 0) wsum_g[m*NH_ + (t >> 4)] = sw;
    }
    __syncthreads();

    const int hh = (t >> 7) * 4;
    const int c  = t & 127;
    const unsigned int* sb = (const unsigned int*)(vbf + (size_t)b*LV_*D_) + c;
#pragma unroll
    for (int h = hh; h < hh + 4; ++h) {
        float e0=0.f, e1=0.f, e2=0.f, e3=0.f;
        float o0=0.f, o1=0.f, o2=0.f, o3=0.f;
#pragma unroll 4
        for (int s = 0; s < 16; ++s) {
            const int base = h*16 + s;
            const int   i0 = cidx[base][0], i1 = cidx[base][1],
                        i2 = cidx[base][2], i3 = cidx[base][3];
            const float w0 = cwt[base][0], w1 = cwt[base][1],
                        w2 = cwt[base][2], w3 = cwt[base][3];
            const unsigned int u0 = sb[(size_t)i0*128];
            const unsigned int u1 = sb[(size_t)i1*128];
            const unsigned int u2 = sb[(size_t)i2*128];
            const unsigned int u3 = sb[(size_t)i3*128];
            e0 += w0*lo2f(u0); o0 += w0*hi2f(u0);
            e1 += w1*lo2f(u1); o1 += w1*hi2f(u1);
            e2 += w2*lo2f(u2); o2 += w2*hi2f(u2);
            e3 += w3*lo2f(u3); o3 += w3*hi2f(u3);
        }
        *(float2*)&svec_g[(size_t)m*(NH_*D_) + h*D_ + 2*c] =
            make_float2((e0+e1)+(e2+e3), (o0+o1)+(o2+o3));
    }
}

// ---------------- 5c. per-head value projection (packed fp32 weights) ------------
__global__ __launch_bounds__(256) void vproj_kernel(
    const float* __restrict__ svec_g, const float* __restrict__ wsum_g,
    const float4* __restrict__ vpwP, const float* __restrict__ vpb,
    float* __restrict__ vo)
{
    __shared__ float sv[4][NH_*D_];    // 32 KB
    const int t = threadIdx.x, m0 = blockIdx.x * 4;
    for (int i = t; i < 4*NH_*D_; i += 256)
        sv[i >> 11][i & 2047] = svec_g[(size_t)m0*(NH_*D_) + i];
    __syncthreads();
    const int h = t >> 5;
    const float4* w4 = vpwP + t;
    float a0 = 0.f, a1 = 0.f, a2 = 0.f, a3 = 0.f;
    for (int c = 0; c < 64; ++c) {
        const float4 wq = w4[c*256];
        const float4 s0 = *(const float4*)&sv[0][h*D_ + c*4];
        const float4 s1 = *(const float4*)&sv[1][h*D_ + c*4];
        const float4 s2 = *(const float4*)&sv[2][h*D_ + c*4];
        const float4 s3 = *(const float4*)&sv[3][h*D_ + c*4];
        a0 += wq.x*s0.x + wq.y*s0.y + wq.z*s0.z + wq.w*s0.w;
        a1 += wq.x*s1.x + wq.y*s1.y + wq.z*s1.z + wq.w*s1.w;
        a2 += wq.x*s2.x + wq.y*s2.y + wq.z*s2.z + wq.w*s2.w;
        a3 += wq.x*s3.x + wq.y*s3.y + wq.z*s3.z + wq.w*s3.w;
    }
    const float bb = vpb[t];
    vo[(size_t)(m0+0)*D_ + t] = a0 + bb*wsum_g[(m0+0)*NH_ + h];
    vo[(size_t)(m0+1)*D_ + t] = a1 + bb*wsum_g[(m0+1)*NH_ + h];
    vo[(size_t)(m0+2)*D_ + t] = a2 + bb*wsum_g[(m0+2)*NH_ + h];
    vo[(size_t)(m0+3)*D_ + t] = a3 + bb*wsum_g[(m0+3)*NH_ + h];
}

// ---------------- 5b. fallback fp32 samp_fuse (if workspace too small) ----------
__global__ __launch_bounds__(256) void samp_fuse_f32_kernel(
    const float* __restrict__ src, const float* __restrict__ Wv,
    const float* __restrict__ vpb,
    const float* __restrict__ loc_f, const float* __restrict__ aw_f,
    float* __restrict__ vo)
{
    __shared__ float svec[NH_][D_];
    __shared__ int   cidx[128][4];
    __shared__ float cwt[128][4];
    __shared__ float wsum[NH_];
    const int m = blockIdx.x, t = threadIdx.x;
    const int b = m / LQ_;

    if (t < 128) {
        const int l = (t >> 2) & 3;
        const int HS[4] = {100,50,25,13}, WS[4] = {152,76,38,19}, S0[4] = {0,15200,19000,19950};
        const int Hh = HS[l], Ww = WS[l], s0 = S0[l];
        const float aw = aw_f[m*128 + t];
        const float x = loc_f[m*256 + 2*t]*Ww - 0.5f;
        const float y = loc_f[m*256 + 2*t + 1]*Hh - 0.5f;
        const float x0f = floorf(x), y0f = floorf(y);
        const int x0 = (int)x0f, y0 = (int)y0f;
        const float fx = x - x0f, fy = y - y0f;
        const int   cx[4] = {x0, x0+1, x0,   x0+1};
        const int   cy[4] = {y0, y0,   y0+1, y0+1};
        const float cw[4] = {(1.f-fx)*(1.f-fy), fx*(1.f-fy), (1.f-fx)*fy, fx*fy};
        float sw = 0.f;
#pragma unroll
        for (int jj = 0; jj < 4; ++jj) {
            const bool valid = (cx[jj] >= 0) & (cx[jj] < Ww) & (cy[jj] >= 0) & (cy[jj] < Hh);
            cidx[t][jj] = valid ? (s0 + cy[jj]*Ww + cx[jj]) : s0;
            float wv = valid ? aw*cw[jj] : 0.f;
            cwt[t][jj] = wv;
            sw += wv;
        }
#pragma unroll
        for (int off = 8; off; off >>= 1) sw += __shfl_xor(sw, off);
        if ((t & 15) == 0) wsum[t >> 4] = sw;
    }
    __syncthreads();

    const float* sb = src + (size_t)b*LV_*D_ + t;
#pragma unroll
    for (int h = 0; h < NH_; ++h) {
        float a0 = 0.f, a1 = 0.f, a2 = 0.f, a3 = 0.f;
#pragma unroll 4
        for (int s = 0; s < 16; ++s) {
            const int base = h*16 + s;
            const int   i0 = cidx[base][0], i1 = cidx[base][1],
                        i2 = cidx[base][2], i3 = cidx[base][3];
            const float w0 = cwt[base][0], w1 = cwt[base][1],
                        w2 = cwt[base][2], w3 = cwt[base][3];
            a0 += w0 * sb[(size_t)i0*D_];
            a1 += w1 * sb[(size_t)i1*D_];
            a2 += w2 * sb[(size_t)i2*D_];
            a3 += w3 * sb[(size_t)i3*D_];
        }
        svec[h][t] = (a0 + a1) + (a2 + a3);
    }
    __syncthreads();

    const int h = t >> 5;
    const float4* w4 = (const float4*)(Wv + t*D_);
    float a = 0.f;
    for (int c = 0; c < 64; ++c) {
        float4 wv = w4[c];
        DOT4(a, wv, &svec[h][c*4]);
    }
    vo[m*D_ + t] = a + vpb[t]*wsum[h];
}

// ---------------- 7. FFN layer 1 (relu, uniform A-loads), cc = blockIdx.y --------
__global__ __launch_bounds__(256) void ffn1_kernel(
    const float* __restrict__ x2, const float4* __restrict__ l1wP,
    const float* __restrict__ b1, float* __restrict__ hid)
{
    const int t = threadIdx.x, m0 = blockIdx.x * 8, cc = blockIdx.y;
    const float* a0 = x2 + (size_t)m0*D_;
    const int j = cc*256 + t;
    float acc[8] = {0,0,0,0,0,0,0,0};
    const float4* w4 = l1wP + j;
#pragma unroll 4
    for (int c = 0; c < 64; ++c) {
        float4 wv = w4[c*1024];
#pragma unroll
        for (int r = 0; r < 8; ++r) DOT4(acc[r], wv, a0 + r*D_ + c*4);
    }
    const float bb = b1[j];
    for (int r = 0; r < 8; ++r) {
        float v = acc[r] + bb;
        hid[(m0+r)*DFF_ + j] = v > 0.f ? v : 0.f;
    }
}

// ---------------- 8. FFN layer 2 + residual + LN (uniform A-loads) ---------------
__global__ __launch_bounds__(256) void ffn2_ln_kernel(
    const float* __restrict__ hid, const float4* __restrict__ l2wP,
    const float* __restrict__ b2, const float* __restrict__ res,
    const float* __restrict__ gw, const float* __restrict__ gb,
    float* __restrict__ out)
{
    __shared__ float2 part[4][8];
    const int t = threadIdx.x, m0 = blockIdx.x * 8;
    const int w = t >> 6, lane = t & 63;
    const float* h0 = hid + (size_t)m0*DFF_;
    float acc[8] = {0,0,0,0,0,0,0,0};
    const float4* w4 = l2wP + t;
#pragma unroll 4
    for (int c = 0; c < 256; ++c) {
        float4 wv = w4[c*256];
#pragma unroll
        for (int r = 0; r < 8; ++r) DOT4(acc[r], wv, h0 + r*DFF_ + c*4);
    }
    const float bb = b2[t], gwv = gw[t], gbv = gb[t];
    float v[8];
#pragma unroll
    for (int r = 0; r < 8; ++r) {
        v[r] = acc[r] + bb + res[(m0+r)*D_+t];
        float s = v[r], ss = v[r]*v[r];
#pragma unroll
        for (int off = 32; off; off >>= 1) {
            s += __shfl_xor(s, off); ss += __shfl_xor(ss, off);
        }
        if (lane == 0) part[w][r] = make_float2(s, ss);
    }
    __syncthreads();
#pragma unroll
    for (int r = 0; r < 8; ++r) {
        float2 p0 = part[0][r], p1 = part[1][r], p2 = part[2][r], p3 = part[3][r];
        float mean = (p0.x+p1.x+p2.x+p3.x) * (1.0f/256.0f);
        float ex2  = (p0.y+p1.y+p2.y+p3.y) * (1.0f/256.0f);
        float var  = ex2 - mean*mean;
        out[(m0+r)*D_+t] = (v[r]-mean) * rsqrtf(var + 1e-5f) * gwv + gbv;
    }
}

extern "C" void kernel_launch(void* const* d_in, const int* in_sizes, int n_in,
                              void* d_out, int out_size, void* d_ws, size_t ws_size,
                              hipStream_t stream) {
    (void)in_sizes; (void)n_in; (void)out_size;
    const float* tgt  = (const float*)d_in[0];
    const float* qpos = (const float*)d_in[1];
    const float* refp = (const float*)d_in[2];
    const float* srcp = (const float*)d_in[3];
    const float* ipw  = (const float*)d_in[4];
    const float* ipb  = (const float*)d_in[5];
    const float* opw  = (const float*)d_in[6];
    const float* opb  = (const float*)d_in[7];
    const float* sow  = (const float*)d_in[8];
    const float* sob  = (const float*)d_in[9];
    const float* aww  = (const float*)d_in[10];
    const float* awb  = (const float*)d_in[11];
    const float* vpw  = (const float*)d_in[12];
    const float* vpb  = (const float*)d_in[13];
    const float* outw = (const float*)d_in[14];
    const float* outb = (const float*)d_in[15];
    const float* l1w  = (const float*)d_in[16];
    const float* l1b  = (const float*)d_in[17];
    const float* l2w  = (const float*)d_in[18];
    const float* l2b  = (const float*)d_in[19];
    const float* n1w  = (const float*)d_in[20];
    const float* n1b  = (const float*)d_in[21];
    const float* n2w  = (const float*)d_in[22];
    const float* n2b  = (const float*)d_in[23];
    const float* n3w  = (const float*)d_in[24];
    const float* n3b  = (const float*)d_in[25];

    float* wsf = (float*)d_ws;
    float* qh   = wsf;
    float* kh   = wsf + 614400;
    float* vh   = wsf + 1228800;
    float* sa   = wsf + 1843200;
    float* x1   = wsf + 2457600;
    float* vo   = wsf + 3072000;
    float* x2   = wsf + 3686400;
    float* hid  = wsf + 4300800;                  // ..6758400
    float* qk   = wsf + 6758400;                  // tgt + qpos
    float* x1q  = wsf + 7372800;                  // x1 + qpos
    float* P0   = wsf + 7987200;                  // packed weights (1,015,808 f)
    float4* ipwP  = (float4*)(P0);
    float4* opwP  = (float4*)(P0 + 196608);
    float4* sowP  = (float4*)(P0 + 262144);
    float4* awwP  = (float4*)(P0 + 327680);
    float4* outwP = (float4*)(P0 + 360448);
    float4* l1wP  = (float4*)(P0 + 425984);
    float4* l2wP  = (float4*)(P0 + 688128);
    float4* vpwP  = (float4*)(P0 + 950272);
    unsigned short* vbf = (unsigned short*)(wsf + 9003008);   // NSRC_ u16
    float* svec_g = wsf + 9003008 + 20681728;     // 4,915,200 floats
    float* wsum_g = svec_g + 4915200;             // 19,200 floats
    const size_t need_bytes = (size_t)(9003008 + 20681728 + 4915200 + 19200) * 4;
    const bool use_bf16 = ws_size >= need_bytes;

    float* xout   = (float*)d_out;            // x   (8,300,256)
    float* locout = xout + 614400;            // loc (8,300,8,4,4,2)
    float* awout  = xout + 1228800;           // aw  (8,300,8,4,4)

    pack_weights_kernel<<<248, 256, 0, stream>>>(
        (const float4*)ipw, (const float4*)opw, (const float4*)sow,
        (const float4*)aww, (const float4*)outw, (const float4*)l1w,
        (const float4*)l2w, (const float4*)vpw,
        ipwP, opwP, sowP, awwP, outwP, l1wP, l2wP, vpwP);
    add_qk_kernel<<<600, 256, 0, stream>>>(tgt, qpos, qk);
    if (use_bf16)
        cvt_bf16_kernel<<<2048, 256, 0, stream>>>(srcp, vbf);
    qkv_kernel<<<dim3(NQ_/8, 3), 256, 0, stream>>>(qk, tgt, ipwP, ipb, qh, kh, vh);
    attn_kernel<<<dim3(BS_*NH_, 5), 256, 0, stream>>>(qh, kh, vh, sa);
    proj_res_ln_kernel<<<NQ_/8, 256, 0, stream>>>(sa, opwP, opb, tgt, n2w, n2b,
                                                  x1, qpos, x1q);
    samp_params_kernel<<<NQ_/8, 256, 0, stream>>>(x1q, sowP, sob, awwP, awb, refp,
                                                  locout, awout);
    if (use_bf16) {
        samp_fuse_bf16_kernel<<<NQ_, 256, 0, stream>>>(vbf, locout, awout, svec_g, wsum_g);
        vproj_kernel<<<NQ_/4, 256, 0, stream>>>(svec_g, wsum_g, vpwP, vpb, vo);
    } else {
        samp_fuse_f32_kernel<<<NQ_, 256, 0, stream>>>(srcp, vpw, vpb, locout, awout, vo);
    }
    proj_res_ln_kernel<<<NQ_/8, 256, 0, stream>>>(vo, outwP, outb, x1, n1w, n1b,
                                                  x2, nullptr, nullptr);
    ffn1_kernel<<<dim3(NQ_/8, 4), 256, 0, stream>>>(x2, l1wP, l1b, hid);
    ffn2_ln_kernel<<<NQ_/8, 256, 0, stream>>>(hid, l2wP, l2b, x2, n3w, n3b, xout);
}

// Round 11
// 592.153 us; speedup vs baseline: 1.3628x; 1.1084x over previous
//
#include <hip/hip_runtime.h>
#include <hip/hip_bf16.h>

#define D_ 256
#define NH_ 8
#define HD_ 32
#define NL_ 4
#define NP_ 4
#define DFF_ 1024
#define BS_ 8
#define LQ_ 300
#define LV_ 20197
#define NQ_ (BS_*LQ_)          // 2400
#define MPAD_ 2432             // 2400 padded to 64-multiple (38*64)
#define NSRC_ (BS_*LV_*D_)     // 41,363,456 floats

typedef short bf16x8 __attribute__((ext_vector_type(8)));
typedef float f32x4  __attribute__((ext_vector_type(4)));

__device__ __forceinline__ float u2f(unsigned int u) {
    union { unsigned int i; float f; } v; v.i = u << 16; return v.f;
}
__device__ __forceinline__ float lo2f(unsigned int u) {
    union { unsigned int i; float f; } v; v.i = u << 16; return v.f;
}
__device__ __forceinline__ float hi2f(unsigned int u) {
    union { unsigned int i; float f; } v; v.i = u & 0xffff0000u; return v.f;
}
__device__ __forceinline__ unsigned short f2bf_bits(float f) {
    __hip_bfloat16 b = __float2bfloat16(f);
    union { __hip_bfloat16 b; unsigned short u; } v; v.b = b; return v.u;
}
__device__ __forceinline__ ushort4 cv4(float4 a) {
    ushort4 o; o.x=f2bf_bits(a.x); o.y=f2bf_bits(a.y); o.z=f2bf_bits(a.z); o.w=f2bf_bits(a.w);
    return o;
}

// acc += dot(w4, a4)
#define DOT4(accum, wv, ap) do { \
    float4 _a = *(const float4*)(ap); \
    accum += wv.x*_a.x + wv.y*_a.y + wv.z*_a.z + wv.w*_a.w; } while(0)

// ---------------- 0a. fp32 -> bf16 conversion of src ----------------
__global__ __launch_bounds__(256) void cvt_bf16_kernel(
    const float* __restrict__ src, unsigned short* __restrict__ vbf)
{
    const int nsrc4 = NSRC_/4;
    for (int i = blockIdx.x*256 + threadIdx.x; i < nsrc4; i += gridDim.x*256) {
        ((ushort4*)vbf)[i] = cv4(((const float4*)src)[i]);
    }
}

// ---------------- 0c. misc bf16 conversions: tgt, tgt+qpos, 3 GEMM weights -------
// segments (float4 units): tgt 153600 | ipw 49152 | l1w 65536 | l2w 65536 = 333824
__global__ __launch_bounds__(256) void cvt_misc_kernel(
    const float4* __restrict__ tgt, const float4* __restrict__ qp,
    const float4* __restrict__ ipw, const float4* __restrict__ l1w,
    const float4* __restrict__ l2w,
    ushort4* __restrict__ tgt_bf, ushort4* __restrict__ qk_bf,
    ushort4* __restrict__ ipw_bf, ushort4* __restrict__ l1w_bf,
    ushort4* __restrict__ l2w_bf)
{
    const int i = blockIdx.x*256 + threadIdx.x;
    if (i < 153600) {
        float4 a = tgt[i], b = qp[i];
        tgt_bf[i] = cv4(a);
        qk_bf[i]  = cv4(make_float4(a.x+b.x, a.y+b.y, a.z+b.z, a.w+b.w));
    } else if (i < 202752) {
        int j = i - 153600; ipw_bf[j] = cv4(ipw[j]);
    } else if (i < 268288) {
        int j = i - 202752; l1w_bf[j] = cv4(l1w[j]);
    } else if (i < 333824) {
        int j = i - 268288; l2w_bf[j] = cv4(l2w[j]);
    }
}

// ---------------- 0b. weight packing (float4 transpose) for VALU-GEMV kernels ----
__global__ __launch_bounds__(256) void pack_weights_kernel(
    const float4* __restrict__ ipw,  const float4* __restrict__ opw,
    const float4* __restrict__ sow,  const float4* __restrict__ aww,
    const float4* __restrict__ outw, const float4* __restrict__ l1w,
    const float4* __restrict__ l2w,  const float4* __restrict__ vpw,
    float4* __restrict__ ipwP,  float4* __restrict__ opwP,
    float4* __restrict__ sowP,  float4* __restrict__ awwP,
    float4* __restrict__ outwP, float4* __restrict__ l1wP,
    float4* __restrict__ l2wP,  float4* __restrict__ vpwP)
{
    __shared__ float4 tile[32][33];
    const int RS[8]  = {768,256,256,128,256,1024,256,256};
    const int C4S[8] = {64, 64, 64, 64, 64, 64, 256, 64};
    const int TCUM[9] = {0,48,64,80,88,104,168,232,248};
    int tb = blockIdx.x, mi = 0;
    while (tb >= TCUM[mi+1]) ++mi;
    const int lt = tb - TCUM[mi];
    const float4* in  = (mi==0)?ipw :(mi==1)?opw :(mi==2)?sow :(mi==3)?aww
                       :(mi==4)?outw:(mi==5)?l1w :(mi==6)?l2w :vpw;
    float4* out       = (mi==0)?ipwP:(mi==1)?opwP:(mi==2)?sowP:(mi==3)?awwP
                       :(mi==4)?outwP:(mi==5)?l1wP:(mi==6)?l2wP:vpwP;
    const int R = RS[mi], C4 = C4S[mi];
    const int tpr = C4 >> 5;
    const int by = lt / tpr, bx = lt % tpr;
    const int tx = threadIdx.x & 31, ty = threadIdx.x >> 5;
#pragma unroll
    for (int i = 0; i < 32; i += 8)
        tile[ty+i][tx] = in[(size_t)(by*32+ty+i)*C4 + bx*32+tx];
    __syncthreads();
#pragma unroll
    for (int i = 0; i < 32; i += 8)
        out[(size_t)(bx*32+ty+i)*R + by*32+tx] = tile[tx][ty+i];
}

// ---------------- G. generic bf16 MFMA GEMM: out[M,Nld] = A[M,K] @ W[N,K]^T + b --
// 64x64 block tile, 4 waves x (16 rows x 64 cols). Fragments direct from global.
// A: lane holds A[m_base+(l&15)][(l>>4)*8 .. +7]; W row n is B col n.
// C/D: col = n_base+nt*16+(l&15), row = m_base+(l>>4)*4+j  (guide m89, verified).
__global__ __launch_bounds__(256) void gemm_bf16_kernel(
    const unsigned short* __restrict__ A,   // [MPAD_, K] bf16
    const unsigned short* __restrict__ W,   // [N, K] bf16
    const float* __restrict__ bias,         // [N]
    float* __restrict__ out,                // [NQ_, Nld] fp32 or null
    unsigned short* __restrict__ out_bf,    // [MPAD_, Nld] bf16 or null
    const int K, const int Nld, const int relu)
{
    const int t = threadIdx.x, wv = t >> 6, l = t & 63;
    const int m_base = blockIdx.x*64 + wv*16;
    const int n_base = blockIdx.y*64;
    const int lr = l & 15, lg = l >> 4;
    const unsigned short* ap = A + (size_t)(m_base + lr)*K + lg*8;
    const unsigned short* wp = W + (size_t)(n_base + lr)*K + lg*8;
    f32x4 ac0 = {0,0,0,0}, ac1 = {0,0,0,0}, ac2 = {0,0,0,0}, ac3 = {0,0,0,0};
    for (int k = 0; k < K; k += 32) {
        bf16x8 a  = *(const bf16x8*)(ap + k);
        bf16x8 b0 = *(const bf16x8*)(wp + k);
        bf16x8 b1 = *(const bf16x8*)(wp + (size_t)16*K + k);
        bf16x8 b2 = *(const bf16x8*)(wp + (size_t)32*K + k);
        bf16x8 b3 = *(const bf16x8*)(wp + (size_t)48*K + k);
        ac0 = __builtin_amdgcn_mfma_f32_16x16x32_bf16(a, b0, ac0, 0, 0, 0);
        ac1 = __builtin_amdgcn_mfma_f32_16x16x32_bf16(a, b1, ac1, 0, 0, 0);
        ac2 = __builtin_amdgcn_mfma_f32_16x16x32_bf16(a, b2, ac2, 0, 0, 0);
        ac3 = __builtin_amdgcn_mfma_f32_16x16x32_bf16(a, b3, ac3, 0, 0, 0);
    }
    const int orow0 = m_base + lg*4;
    const int ocol  = n_base + lr;
    const float b0v = bias[ocol], b1v = bias[ocol+16],
                b2v = bias[ocol+32], b3v = bias[ocol+48];
#pragma unroll
    for (int j = 0; j < 4; ++j) {
        const int row = orow0 + j;
        if (row < NQ_) {
            float v0 = ac0[j] + b0v, v1 = ac1[j] + b1v,
                  v2 = ac2[j] + b2v, v3 = ac3[j] + b3v;
            if (relu) {
                v0 = fmaxf(v0, 0.f); v1 = fmaxf(v1, 0.f);
                v2 = fmaxf(v2, 0.f); v3 = fmaxf(v3, 0.f);
            }
            const size_t base = (size_t)row*Nld + ocol;
            if (out) {
                out[base]    = v0; out[base+16] = v1;
                out[base+32] = v2; out[base+48] = v3;
            }
            if (out_bf) {
                out_bf[base]    = f2bf_bits(v0); out_bf[base+16] = f2bf_bits(v1);
                out_bf[base+32] = f2bf_bits(v2); out_bf[base+48] = f2bf_bits(v3);
            }
        }
    }
}

// ---------------- 2. Self attention (no inner barriers; grid.y=5) ----------------
__global__ __launch_bounds__(256) void attn_kernel(
    const float* __restrict__ qh, const float* __restrict__ kh,
    const float* __restrict__ vh, float* __restrict__ sa)
{
    __shared__ unsigned short khl[LQ_][HD_+2];
    __shared__ unsigned short vhl[LQ_][HD_+2];
    __shared__ float sc[4][LQ_];
    __shared__ float qbuf[4][HD_];
    const int b = blockIdx.x >> 3, h = blockIdx.x & 7, chunk = blockIdx.y;
    const int t = threadIdx.x, w = t >> 6, lane = t & 63;
    for (int i = t; i < LQ_*HD_; i += 256) {
        int kq = i >> 5, d = i & 31;
        khl[kq][d] = f2bf_bits(kh[(b*LQ_ + kq)*D_ + h*HD_ + d]);
        vhl[kq][d] = f2bf_bits(vh[(b*LQ_ + kq)*D_ + h*HD_ + d]);
    }
    __syncthreads();
    const float scale = 0.17677669529663687f;  // 1/sqrt(32)
    for (int qi = 0; qi < 15; ++qi) {
        const int q = chunk*60 + w*15 + qi;
        if (lane < HD_) qbuf[w][lane] = qh[(b*LQ_ + q)*D_ + h*HD_ + lane];
        float qv[HD_];
#pragma unroll
        for (int d2 = 0; d2 < HD_; ++d2) qv[d2] = qbuf[w][d2];
        float mx = -1e30f;
        for (int k = lane; k < LQ_; k += 64) {
            float s = 0.f;
#pragma unroll
            for (int d2 = 0; d2 < HD_; ++d2) s += qv[d2]*u2f(khl[k][d2]);
            s *= scale;
            sc[w][k] = s;
            mx = fmaxf(mx, s);
        }
#pragma unroll
        for (int off = 32; off; off >>= 1) mx = fmaxf(mx, __shfl_xor(mx, off));
        float lsum = 0.f;
        for (int k = lane; k < LQ_; k += 64) {
            float e = __expf(sc[w][k] - mx);
            sc[w][k] = e; lsum += e;
        }
#pragma unroll
        for (int off = 32; off; off >>= 1) lsum += __shfl_xor(lsum, off);
        const int d = lane & 31, half = lane >> 5;
        float acc = 0.f;
        for (int k = half*150; k < half*150 + 150; ++k) acc += sc[w][k]*u2f(vhl[k][d]);
        acc += __shfl_down(acc, 32);
        if (lane < 32) sa[(b*LQ_ + q)*D_ + h*HD_ + d] = acc / lsum;
    }
}

// ---------------- 3/6. proj + residual + LN (uniform scalar A-loads) -------------
__global__ __launch_bounds__(256) void proj_res_ln_kernel(
    const float* __restrict__ A, const float4* __restrict__ WP,
    const float* __restrict__ bias, const float* __restrict__ res,
    const float* __restrict__ gw, const float* __restrict__ gb,
    float* __restrict__ out, const float* __restrict__ qp,
    float* __restrict__ outq, unsigned short* __restrict__ out_bf)
{
    __shared__ float2 part[4][8];
    const int t = threadIdx.x, m0 = blockIdx.x * 8;
    const int w = t >> 6, lane = t & 63;
    const float* a0 = A + (size_t)m0*D_;
    float acc[8] = {0,0,0,0,0,0,0,0};
    const float4* w4 = WP + t;
#pragma unroll 4
    for (int c = 0; c < 64; ++c) {
        float4 wv = w4[c*256];
#pragma unroll
        for (int r = 0; r < 8; ++r) DOT4(acc[r], wv, a0 + r*D_ + c*4);
    }
    const float bb = bias[t], gwv = gw[t], gbv = gb[t];
    float v[8];
#pragma unroll
    for (int r = 0; r < 8; ++r) {
        v[r] = acc[r] + bb + res[(m0+r)*D_+t];
        float s = v[r], ss = v[r]*v[r];
#pragma unroll
        for (int off = 32; off; off >>= 1) {
            s += __shfl_xor(s, off); ss += __shfl_xor(ss, off);
        }
        if (lane == 0) part[w][r] = make_float2(s, ss);
    }
    __syncthreads();
#pragma unroll
    for (int r = 0; r < 8; ++r) {
        float2 p0 = part[0][r], p1 = part[1][r], p2 = part[2][r], p3 = part[3][r];
        float mean = (p0.x+p1.x+p2.x+p3.x) * (1.0f/256.0f);
        float ex2  = (p0.y+p1.y+p2.y+p3.y) * (1.0f/256.0f);
        float var  = ex2 - mean*mean;
        float o = (v[r]-mean) * rsqrtf(var + 1e-5f) * gwv + gbv;
        out[(m0+r)*D_+t] = o;
        if (outq)   outq[(m0+r)*D_+t] = o + qp[(m0+r)*D_+t];
        if (out_bf) out_bf[(m0+r)*D_+t] = f2bf_bits(o);
    }
}

// ---------------- 8b. residual + LN (post-ffn2) ----------------
__global__ __launch_bounds__(256) void res_ln_kernel(
    const float* __restrict__ y, const float* __restrict__ res,
    const float* __restrict__ gw, const float* __restrict__ gb,
    float* __restrict__ out)
{
    __shared__ float2 part[4][8];
    const int t = threadIdx.x, m0 = blockIdx.x * 8;
    const int w = t >> 6, lane = t & 63;
    const float gwv = gw[t], gbv = gb[t];
    float v[8];
#pragma unroll
    for (int r = 0; r < 8; ++r) {
        v[r] = y[(m0+r)*D_+t] + res[(m0+r)*D_+t];
        float s = v[r], ss = v[r]*v[r];
#pragma unroll
        for (int off = 32; off; off >>= 1) {
            s += __shfl_xor(s, off); ss += __shfl_xor(ss, off);
        }
        if (lane == 0) part[w][r] = make_float2(s, ss);
    }
    __syncthreads();
#pragma unroll
    for (int r = 0; r < 8; ++r) {
        float2 p0 = part[0][r], p1 = part[1][r], p2 = part[2][r], p3 = part[3][r];
        float mean = (p0.x+p1.x+p2.x+p3.x) * (1.0f/256.0f);
        float ex2  = (p0.y+p1.y+p2.y+p3.y) * (1.0f/256.0f);
        float var  = ex2 - mean*mean;
        out[(m0+r)*D_+t] = (v[r]-mean) * rsqrtf(var + 1e-5f) * gwv + gbv;
    }
}

// ---------------- 4. sampling offsets / aw / loc (uniform A-loads from x1q) ------
__global__ __launch_bounds__(256) void samp_params_kernel(
    const float* __restrict__ x1q,
    const float4* __restrict__ sowP, const float* __restrict__ so_b,
    const float4* __restrict__ awwP, const float* __restrict__ aw_b,
    const float* __restrict__ refp,
    float* __restrict__ loc_out, float* __restrict__ aw_out)
{
    __shared__ float logits[8][128];
    const int t = threadIdx.x, m0 = blockIdx.x * 8;
    const float* a0 = x1q + (size_t)m0*D_;
    {   // offsets -> loc
        float acc[8] = {0,0,0,0,0,0,0,0};
        const float4* w4 = sowP + t;
#pragma unroll 4
        for (int c = 0; c < 64; ++c) {
            float4 wv = w4[c*256];
#pragma unroll
            for (int r = 0; r < 8; ++r) DOT4(acc[r], wv, a0 + r*D_ + c*4);
        }
        const float ob = so_b[t];
        const int c_ = t & 1, l_ = (t >> 3) & 3;
        float nrm;
        if (c_ == 0) nrm = (l_==0)?152.f:(l_==1)?76.f:(l_==2)?38.f:19.f;
        else         nrm = (l_==0)?100.f:(l_==1)?50.f:(l_==2)?25.f:13.f;
        for (int r = 0; r < 8; ++r) {
            int m = m0 + r;
            float off = acc[r] + ob;
            loc_out[m*256 + t] = refp[(m*NL_ + l_)*2 + c_] + off / nrm;
        }
    }
    if (t < 128) {  // attention-weight logits
        float acc[8] = {0,0,0,0,0,0,0,0};
        const float4* w4 = awwP + t;
#pragma unroll 4
        for (int c = 0; c < 64; ++c) {
            float4 wv = w4[c*128];
#pragma unroll
            for (int r = 0; r < 8; ++r) DOT4(acc[r], wv, a0 + r*D_ + c*4);
        }
        const float ab = aw_b[t];
        for (int r = 0; r < 8; ++r) logits[r][t] = acc[r] + ab;
    }
    __syncthreads();
    if (t < 128) {  // softmax over the 16 (l,p) per head
        const int g0 = (t >> 4) << 4;
        for (int r = 0; r < 8; ++r) {
            float mx = -1e30f;
            for (int j = 0; j < 16; ++j) mx = fmaxf(mx, logits[r][g0+j]);
            float s = 0.f;
            for (int j = 0; j < 16; ++j) s += __expf(logits[r][g0+j] - mx);
            aw_out[(m0+r)*128 + t] = __expf(logits[r][t] - mx) / s;
        }
    }
}

// ---------------- 5. deformable sampling gather (bf16), R5-proven ----------------
__global__ __launch_bounds__(256) void samp_fuse_bf16_kernel(
    const unsigned short* __restrict__ vbf,
    const float* __restrict__ loc_f, const float* __restrict__ aw_f,
    float* __restrict__ svec_g, float* __restrict__ wsum_g)
{
    __shared__ int   cidx[128][4];
    __shared__ float cwt[128][4];
    const int m = blockIdx.x, t = threadIdx.x;
    const int b = m / LQ_;

    if (t < 128) {   // t = h*16 + l*4 + p
        const int l = (t >> 2) & 3;
        const int HS[4] = {100,50,25,13}, WS[4] = {152,76,38,19}, S0[4] = {0,15200,19000,19950};
        const int Hh = HS[l], Ww = WS[l], s0 = S0[l];
        const float aw = aw_f[m*128 + t];
        const float x = loc_f[m*256 + 2*t]*Ww - 0.5f;
        const float y = loc_f[m*256 + 2*t + 1]*Hh - 0.5f;
        const float x0f = floorf(x), y0f = floorf(y);
        const int x0 = (int)x0f, y0 = (int)y0f;
        const float fx = x - x0f, fy = y - y0f;
        const int   cx[4] = {x0, x0+1, x0,   x0+1};
        const int   cy[4] = {y0, y0,   y0+1, y0+1};
        const float cw[4] = {(1.f-fx)*(1.f-fy), fx*(1.f-fy), (1.f-fx)*fy, fx*fy};
        float sw = 0.f;
#pragma unroll
        for (int j = 0; j < 4; ++j) {
            const bool valid = (cx[j] >= 0) & (cx[j] < Ww) & (cy[j] >= 0) & (cy[j] < Hh);
            cidx[t][j] = valid ? (s0 + cy[j]*Ww + cx[j]) : s0;
            float wv = valid ? aw*cw[j] : 0.f;
            cwt[t][j] = wv;
            sw += wv;
        }
#pragma unroll
        for (int off = 8; off; off >>= 1) sw += __shfl_xor(sw, off);
        if ((t & 15) == 0) wsum_g[m*NH_ + (t >> 4)] = sw;
    }
    __syncthreads();

    const int hh = (t >> 7) * 4;
    const int c  = t & 127;
    const unsigned int* sb = (const unsigned int*)(vbf + (size_t)b*LV_*D_) + c;
#pragma unroll
    for (int h = hh; h < hh + 4; ++h) {
        float e0=0.f, e1=0.f, e2=0.f, e3=0.f;
        float o0=0.f, o1=0.f, o2=0.f, o3=0.f;
#pragma unroll 4
        for (int s = 0; s < 16; ++s) {
            const int base = h*16 + s;
            const int   i0 = cidx[base][0], i1 = cidx[base][1],
                        i2 = cidx[base][2], i3 = cidx[base][3];
            const float w0 = cwt[base][0], w1 = cwt[base][1],
                        w2 = cwt[base][2], w3 = cwt[base][3];
            const unsigned int u0 = sb[(size_t)i0*128];
            const unsigned int u1 = sb[(size_t)i1*128];
            const unsigned int u2 = sb[(size_t)i2*128];
            const unsigned int u3 = sb[(size_t)i3*128];
            e0 += w0*lo2f(u0); o0 += w0*hi2f(u0);
            e1 += w1*lo2f(u1); o1 += w1*hi2f(u1);
            e2 += w2*lo2f(u2); o2 += w2*hi2f(u2);
            e3 += w3*lo2f(u3); o3 += w3*hi2f(u3);
        }
        *(float2*)&svec_g[(size_t)m*(NH_*D_) + h*D_ + 2*c] =
            make_float2((e0+e1)+(e2+e3), (o0+o1)+(o2+o3));
    }
}

// ---------------- 5c. per-head value projection (packed fp32 weights) ------------
__global__ __launch_bounds__(256) void vproj_kernel(
    const float* __restrict__ svec_g, const float* __restrict__ wsum_g,
    const float4* __restrict__ vpwP, const float* __restrict__ vpb,
    float* __restrict__ vo)
{
    __shared__ float sv[4][NH_*D_];    // 32 KB
    const int t = threadIdx.x, m0 = blockIdx.x * 4;
    for (int i = t; i < 4*NH_*D_; i += 256)
        sv[i >> 11][i & 2047] = svec_g[(size_t)m0*(NH_*D_) + i];
    __syncthreads();
    const int h = t >> 5;
    const float4* w4 = vpwP + t;
    float a0 = 0.f, a1 = 0.f, a2 = 0.f, a3 = 0.f;
    for (int c = 0; c < 64; ++c) {
        const float4 wq = w4[c*256];
        const float4 s0 = *(const float4*)&sv[0][h*D_ + c*4];
        const float4 s1 = *(const float4*)&sv[1][h*D_ + c*4];
        const float4 s2 = *(const float4*)&sv[2][h*D_ + c*4];
        const float4 s3 = *(const float4*)&sv[3][h*D_ + c*4];
        a0 += wq.x*s0.x + wq.y*s0.y + wq.z*s0.z + wq.w*s0.w;
        a1 += wq.x*s1.x + wq.y*s1.y + wq.z*s1.z + wq.w*s1.w;
        a2 += wq.x*s2.x + wq.y*s2.y + wq.z*s2.z + wq.w*s2.w;
        a3 += wq.x*s3.x + wq.y*s3.y + wq.z*s3.z + wq.w*s3.w;
    }
    const float bb = vpb[t];
    vo[(size_t)(m0+0)*D_ + t] = a0 + bb*wsum_g[(m0+0)*NH_ + h];
    vo[(size_t)(m0+1)*D_ + t] = a1 + bb*wsum_g[(m0+1)*NH_ + h];
    vo[(size_t)(m0+2)*D_ + t] = a2 + bb*wsum_g[(m0+2)*NH_ + h];
    vo[(size_t)(m0+3)*D_ + t] = a3 + bb*wsum_g[(m0+3)*NH_ + h];
}

extern "C" void kernel_launch(void* const* d_in, const int* in_sizes, int n_in,
                              void* d_out, int out_size, void* d_ws, size_t ws_size,
                              hipStream_t stream) {
    (void)in_sizes; (void)n_in; (void)out_size; (void)ws_size;
    const float* tgt  = (const float*)d_in[0];
    const float* qpos = (const float*)d_in[1];
    const float* refp = (const float*)d_in[2];
    const float* srcp = (const float*)d_in[3];
    const float* ipw  = (const float*)d_in[4];
    const float* ipb  = (const float*)d_in[5];
    const float* opw  = (const float*)d_in[6];
    const float* opb  = (const float*)d_in[7];
    const float* sow  = (const float*)d_in[8];
    const float* sob  = (const float*)d_in[9];
    const float* aww  = (const float*)d_in[10];
    const float* awb  = (const float*)d_in[11];
    const float* vpw  = (const float*)d_in[12];
    const float* vpb  = (const float*)d_in[13];
    const float* outw = (const float*)d_in[14];
    const float* outb = (const float*)d_in[15];
    const float* l1w  = (const float*)d_in[16];
    const float* l1b  = (const float*)d_in[17];
    const float* l2w  = (const float*)d_in[18];
    const float* l2b  = (const float*)d_in[19];
    const float* n1w  = (const float*)d_in[20];
    const float* n1b  = (const float*)d_in[21];
    const float* n2w  = (const float*)d_in[22];
    const float* n2b  = (const float*)d_in[23];
    const float* n3w  = (const float*)d_in[24];
    const float* n3b  = (const float*)d_in[25];

    float* wsf = (float*)d_ws;
    float* qh   = wsf;                        //  614400
    float* kh   = wsf + 614400;
    float* vh   = wsf + 1228800;
    float* sa   = wsf + 1843200;
    float* x1   = wsf + 2457600;
    float* vo   = wsf + 3072000;
    float* x2   = wsf + 3686400;
    float* y3   = wsf + 4300800;              //  614400 (ffn2 pre-LN)
    float* x1q  = wsf + 4915200;              //  614400
    float* P0   = wsf + 5529600;              // packed fp32 weights 1,015,808
    float4* ipwP  = (float4*)(P0);
    float4* opwP  = (float4*)(P0 + 196608);
    float4* sowP  = (float4*)(P0 + 262144);
    float4* awwP  = (float4*)(P0 + 327680);
    float4* outwP = (float4*)(P0 + 360448);
    float4* l1wP  = (float4*)(P0 + 425984);
    float4* l2wP  = (float4*)(P0 + 688128);
    float4* vpwP  = (float4*)(P0 + 950272);
    // bf16 buffers (u16 units), offsets in floats from wsf
    unsigned short* hid_bf = (unsigned short*)(wsf + 6545408);  // MPAD_*1024 u16 = 1,245,184 f
    unsigned short* tgt_bf = (unsigned short*)(wsf + 7790592);  // MPAD_*256 u16 = 311,296 f
    unsigned short* qk_bf  = (unsigned short*)(wsf + 8101888);  // 311,296 f
    unsigned short* x2_bf  = (unsigned short*)(wsf + 8413184);  // 311,296 f
    unsigned short* ipw_bf = (unsigned short*)(wsf + 8724480);  // 196,608 u16 = 98,304 f
    unsigned short* l1w_bf = (unsigned short*)(wsf + 8822784);  // 262,144 u16 = 131,072 f
    unsigned short* l2w_bf = (unsigned short*)(wsf + 8953856);  // 262,144 u16 = 131,072 f
    unsigned short* vbf    = (unsigned short*)(wsf + 9084928);  // NSRC_ u16 = 20,681,728 f
    float* svec_g = wsf + 9084928 + 20681728;                   // 4,915,200  (R10 BUG: was +10340864, overlapped vbf!)
    float* wsum_g = svec_g + 4915200;                           // 19,200

    float* xout   = (float*)d_out;            // x   (8,300,256)
    float* locout = xout + 614400;            // loc (8,300,8,4,4,2)
    float* awout  = xout + 1228800;           // aw  (8,300,8,4,4)

    pack_weights_kernel<<<248, 256, 0, stream>>>(
        (const float4*)ipw, (const float4*)opw, (const float4*)sow,
        (const float4*)aww, (const float4*)outw, (const float4*)l1w,
        (const float4*)l2w, (const float4*)vpw,
        ipwP, opwP, sowP, awwP, outwP, l1wP, l2wP, vpwP);
    cvt_misc_kernel<<<1304, 256, 0, stream>>>(
        (const float4*)tgt, (const float4*)qpos, (const float4*)ipw,
        (const float4*)l1w, (const float4*)l2w,
        (ushort4*)tgt_bf, (ushort4*)qk_bf, (ushort4*)ipw_bf,
        (ushort4*)l1w_bf, (ushort4*)l2w_bf);
    cvt_bf16_kernel<<<2048, 256, 0, stream>>>(srcp, vbf);

    // QKV: three N=256 GEMMs sharing the generic kernel
    gemm_bf16_kernel<<<dim3(38, 4), 256, 0, stream>>>(qk_bf,  ipw_bf,          ipb,       qh, nullptr, 256, 256, 0);
    gemm_bf16_kernel<<<dim3(38, 4), 256, 0, stream>>>(qk_bf,  ipw_bf + 65536,  ipb + 256, kh, nullptr, 256, 256, 0);
    gemm_bf16_kernel<<<dim3(38, 4), 256, 0, stream>>>(tgt_bf, ipw_bf + 131072, ipb + 512, vh, nullptr, 256, 256, 0);

    attn_kernel<<<dim3(BS_*NH_, 5), 256, 0, stream>>>(qh, kh, vh, sa);
    proj_res_ln_kernel<<<NQ_/8, 256, 0, stream>>>(sa, opwP, opb, tgt, n2w, n2b,
                                                  x1, qpos, x1q, nullptr);
    samp_params_kernel<<<NQ_/8, 256, 0, stream>>>(x1q, sowP, sob, awwP, awb, refp,
                                                  locout, awout);
    samp_fuse_bf16_kernel<<<NQ_, 256, 0, stream>>>(vbf, locout, awout, svec_g, wsum_g);
    vproj_kernel<<<NQ_/4, 256, 0, stream>>>(svec_g, wsum_g, vpwP, vpb, vo);
    proj_res_ln_kernel<<<NQ_/8, 256, 0, stream>>>(vo, outwP, outb, x1, n1w, n1b,
                                                  x2, nullptr, nullptr, x2_bf);
    // FFN via MFMA
    gemm_bf16_kernel<<<dim3(38, 16), 256, 0, stream>>>(x2_bf,  l1w_bf, l1b, nullptr, hid_bf, 256, 1024, 1);
    gemm_bf16_kernel<<<dim3(38, 4),  256, 0, stream>>>(hid_bf, l2w_bf, l2b, y3, nullptr, 1024, 256, 0);
    res_ln_kernel<<<NQ_/8, 256, 0, stream>>>(y3, x2, n3w, n3b, xout);
}

// Round 12
// 550.919 us; speedup vs baseline: 1.4648x; 1.0748x over previous
//
#include <hip/hip_runtime.h>
#include <hip/hip_bf16.h>

#define D_ 256
#define NH_ 8
#define HD_ 32
#define NL_ 4
#define NP_ 4
#define DFF_ 1024
#define BS_ 8
#define LQ_ 300
#define LV_ 20197
#define NQ_ (BS_*LQ_)          // 2400
#define MPAD_ 2432             // 2400 padded to 64-multiple (38*64)
#define NSRC_ (BS_*LV_*D_)     // 41,363,456 floats

typedef short bf16x8 __attribute__((ext_vector_type(8)));
typedef float f32x4  __attribute__((ext_vector_type(4)));

__device__ __forceinline__ float u2f(unsigned int u) {
    union { unsigned int i; float f; } v; v.i = u << 16; return v.f;
}
__device__ __forceinline__ float lo2f(unsigned int u) {
    union { unsigned int i; float f; } v; v.i = u << 16; return v.f;
}
__device__ __forceinline__ float hi2f(unsigned int u) {
    union { unsigned int i; float f; } v; v.i = u & 0xffff0000u; return v.f;
}
__device__ __forceinline__ unsigned short f2bf_bits(float f) {
    __hip_bfloat16 b = __float2bfloat16(f);
    union { __hip_bfloat16 b; unsigned short u; } v; v.b = b; return v.u;
}
__device__ __forceinline__ ushort4 cv4(float4 a) {
    ushort4 o; o.x=f2bf_bits(a.x); o.y=f2bf_bits(a.y); o.z=f2bf_bits(a.z); o.w=f2bf_bits(a.w);
    return o;
}

// ---------------- 0a. fp32 -> bf16 conversion of src ----------------
__global__ __launch_bounds__(256) void cvt_bf16_kernel(
    const float* __restrict__ src, unsigned short* __restrict__ vbf)
{
    const int nsrc4 = NSRC_/4;
    for (int i = blockIdx.x*256 + threadIdx.x; i < nsrc4; i += gridDim.x*256) {
        ((ushort4*)vbf)[i] = cv4(((const float4*)src)[i]);
    }
}

// ---------------- 0c. bf16 conversions: tgt, tgt+qpos, 7 GEMM weights ------------
// segments (float4 units): tgt 153600 | ipw 49152 | l1w 65536 | l2w 65536
//                        | opw 16384 | outw 16384 | sow 16384 | aww 8192 = 391168
__global__ __launch_bounds__(256) void cvt_misc_kernel(
    const float4* __restrict__ tgt, const float4* __restrict__ qp,
    const float4* __restrict__ ipw, const float4* __restrict__ l1w,
    const float4* __restrict__ l2w, const float4* __restrict__ opw,
    const float4* __restrict__ outw, const float4* __restrict__ sow,
    const float4* __restrict__ aww,
    ushort4* __restrict__ tgt_bf, ushort4* __restrict__ qk_bf,
    ushort4* __restrict__ ipw_bf, ushort4* __restrict__ l1w_bf,
    ushort4* __restrict__ l2w_bf, ushort4* __restrict__ opw_bf,
    ushort4* __restrict__ outw_bf, ushort4* __restrict__ sow_bf,
    ushort4* __restrict__ aww_bf)
{
    const int i = blockIdx.x*256 + threadIdx.x;
    if (i < 153600) {
        float4 a = tgt[i], b = qp[i];
        tgt_bf[i] = cv4(a);
        qk_bf[i]  = cv4(make_float4(a.x+b.x, a.y+b.y, a.z+b.z, a.w+b.w));
    } else if (i < 202752) { int j = i - 153600; ipw_bf[j]  = cv4(ipw[j]);
    } else if (i < 268288) { int j = i - 202752; l1w_bf[j]  = cv4(l1w[j]);
    } else if (i < 333824) { int j = i - 268288; l2w_bf[j]  = cv4(l2w[j]);
    } else if (i < 350208) { int j = i - 333824; opw_bf[j]  = cv4(opw[j]);
    } else if (i < 366592) { int j = i - 350208; outw_bf[j] = cv4(outw[j]);
    } else if (i < 382976) { int j = i - 366592; sow_bf[j]  = cv4(sow[j]);
    } else if (i < 391168) { int j = i - 382976; aww_bf[j]  = cv4(aww[j]);
    }
}

// ---------------- 0b. pack vpw (float4 transpose) for vproj ----------------
__global__ __launch_bounds__(256) void pack_vpw_kernel(
    const float4* __restrict__ vpw, float4* __restrict__ vpwP)
{
    __shared__ float4 tile[32][33];
    const int by = blockIdx.x >> 1, bx = blockIdx.x & 1;   // 8 x 2 tiles
    const int tx = threadIdx.x & 31, ty = threadIdx.x >> 5;
#pragma unroll
    for (int i = 0; i < 32; i += 8)
        tile[ty+i][tx] = vpw[(size_t)(by*32+ty+i)*64 + bx*32+tx];
    __syncthreads();
#pragma unroll
    for (int i = 0; i < 32; i += 8)
        vpwP[(size_t)(bx*32+ty+i)*256 + by*32+tx] = tile[tx][ty+i];
}

// ---------------- G. generic bf16 MFMA GEMM: out[M,Nld] = A[M,K] @ W[N,K]^T + b --
// 64x64 block tile, 4 waves x (16 rows x 64 cols). Fragments direct from global.
__global__ __launch_bounds__(256) void gemm_bf16_kernel(
    const unsigned short* __restrict__ A,   // [MPAD_, K] bf16
    const unsigned short* __restrict__ W,   // [N, K] bf16
    const float* __restrict__ bias,         // [N]
    float* __restrict__ out,                // [NQ_, Nld] fp32 or null
    unsigned short* __restrict__ out_bf,    // [MPAD_, Nld] bf16 or null
    const int K, const int Nld, const int relu)
{
    const int t = threadIdx.x, wv = t >> 6, l = t & 63;
    const int m_base = blockIdx.x*64 + wv*16;
    const int n_base = blockIdx.y*64;
    const int lr = l & 15, lg = l >> 4;
    const unsigned short* ap = A + (size_t)(m_base + lr)*K + lg*8;
    const unsigned short* wp = W + (size_t)(n_base + lr)*K + lg*8;
    f32x4 ac0 = {0,0,0,0}, ac1 = {0,0,0,0}, ac2 = {0,0,0,0}, ac3 = {0,0,0,0};
    for (int k = 0; k < K; k += 32) {
        bf16x8 a  = *(const bf16x8*)(ap + k);
        bf16x8 b0 = *(const bf16x8*)(wp + k);
        bf16x8 b1 = *(const bf16x8*)(wp + (size_t)16*K + k);
        bf16x8 b2 = *(const bf16x8*)(wp + (size_t)32*K + k);
        bf16x8 b3 = *(const bf16x8*)(wp + (size_t)48*K + k);
        ac0 = __builtin_amdgcn_mfma_f32_16x16x32_bf16(a, b0, ac0, 0, 0, 0);
        ac1 = __builtin_amdgcn_mfma_f32_16x16x32_bf16(a, b1, ac1, 0, 0, 0);
        ac2 = __builtin_amdgcn_mfma_f32_16x16x32_bf16(a, b2, ac2, 0, 0, 0);
        ac3 = __builtin_amdgcn_mfma_f32_16x16x32_bf16(a, b3, ac3, 0, 0, 0);
    }
    const int orow0 = m_base + lg*4;
    const int ocol  = n_base + lr;
    const float b0v = bias[ocol], b1v = bias[ocol+16],
                b2v = bias[ocol+32], b3v = bias[ocol+48];
#pragma unroll
    for (int j = 0; j < 4; ++j) {
        const int row = orow0 + j;
        if (row < NQ_) {
            float v0 = ac0[j] + b0v, v1 = ac1[j] + b1v,
                  v2 = ac2[j] + b2v, v3 = ac3[j] + b3v;
            if (relu) {
                v0 = fmaxf(v0, 0.f); v1 = fmaxf(v1, 0.f);
                v2 = fmaxf(v2, 0.f); v3 = fmaxf(v3, 0.f);
            }
            const size_t base = (size_t)row*Nld + ocol;
            if (out) {
                out[base]    = v0; out[base+16] = v1;
                out[base+32] = v2; out[base+48] = v3;
            }
            if (out_bf) {
                out_bf[base]    = f2bf_bits(v0); out_bf[base+16] = f2bf_bits(v1);
                out_bf[base+32] = f2bf_bits(v2); out_bf[base+48] = f2bf_bits(v3);
            }
        }
    }
}

// ---------------- 2. Self attention (no inner barriers; grid.y=5) -> bf16 out ----
__global__ __launch_bounds__(256) void attn_kernel(
    const float* __restrict__ qh, const float* __restrict__ kh,
    const float* __restrict__ vh, unsigned short* __restrict__ sa_bf)
{
    __shared__ unsigned short khl[LQ_][HD_+2];
    __shared__ unsigned short vhl[LQ_][HD_+2];
    __shared__ float sc[4][LQ_];
    __shared__ float qbuf[4][HD_];
    const int b = blockIdx.x >> 3, h = blockIdx.x & 7, chunk = blockIdx.y;
    const int t = threadIdx.x, w = t >> 6, lane = t & 63;
    for (int i = t; i < LQ_*HD_; i += 256) {
        int kq = i >> 5, d = i & 31;
        khl[kq][d] = f2bf_bits(kh[(b*LQ_ + kq)*D_ + h*HD_ + d]);
        vhl[kq][d] = f2bf_bits(vh[(b*LQ_ + kq)*D_ + h*HD_ + d]);
    }
    __syncthreads();
    const float scale = 0.17677669529663687f;  // 1/sqrt(32)
    for (int qi = 0; qi < 15; ++qi) {
        const int q = chunk*60 + w*15 + qi;
        if (lane < HD_) qbuf[w][lane] = qh[(b*LQ_ + q)*D_ + h*HD_ + lane];
        float qv[HD_];
#pragma unroll
        for (int d2 = 0; d2 < HD_; ++d2) qv[d2] = qbuf[w][d2];
        float mx = -1e30f;
        for (int k = lane; k < LQ_; k += 64) {
            float s = 0.f;
#pragma unroll
            for (int d2 = 0; d2 < HD_; ++d2) s += qv[d2]*u2f(khl[k][d2]);
            s *= scale;
            sc[w][k] = s;
            mx = fmaxf(mx, s);
        }
#pragma unroll
        for (int off = 32; off; off >>= 1) mx = fmaxf(mx, __shfl_xor(mx, off));
        float lsum = 0.f;
        for (int k = lane; k < LQ_; k += 64) {
            float e = __expf(sc[w][k] - mx);
            sc[w][k] = e; lsum += e;
        }
#pragma unroll
        for (int off = 32; off; off >>= 1) lsum += __shfl_xor(lsum, off);
        const int d = lane & 31, half = lane >> 5;
        float acc = 0.f;
        for (int k = half*150; k < half*150 + 150; ++k) acc += sc[w][k]*u2f(vhl[k][d]);
        acc += __shfl_down(acc, 32);
        if (lane < 32) sa_bf[(size_t)(b*LQ_ + q)*D_ + h*HD_ + d] = f2bf_bits(acc / lsum);
    }
}

// ---------------- R. residual + LayerNorm epilogue (shared by all 3 LN sites) ----
// out = LN(y + res); optional outq_bf = bf16(out + qp); optional out_bf = bf16(out)
__global__ __launch_bounds__(256) void res_ln_kernel(
    const float* __restrict__ y, const float* __restrict__ res,
    const float* __restrict__ gw, const float* __restrict__ gb,
    float* __restrict__ out, const float* __restrict__ qp,
    unsigned short* __restrict__ outq_bf, unsigned short* __restrict__ out_bf)
{
    __shared__ float2 part[4][8];
    const int t = threadIdx.x, m0 = blockIdx.x * 8;
    const int w = t >> 6, lane = t & 63;
    const float gwv = gw[t], gbv = gb[t];
    float v[8];
#pragma unroll
    for (int r = 0; r < 8; ++r) {
        v[r] = y[(m0+r)*D_+t] + res[(m0+r)*D_+t];
        float s = v[r], ss = v[r]*v[r];
#pragma unroll
        for (int off = 32; off; off >>= 1) {
            s += __shfl_xor(s, off); ss += __shfl_xor(ss, off);
        }
        if (lane == 0) part[w][r] = make_float2(s, ss);
    }
    __syncthreads();
#pragma unroll
    for (int r = 0; r < 8; ++r) {
        float2 p0 = part[0][r], p1 = part[1][r], p2 = part[2][r], p3 = part[3][r];
        float mean = (p0.x+p1.x+p2.x+p3.x) * (1.0f/256.0f);
        float ex2  = (p0.y+p1.y+p2.y+p3.y) * (1.0f/256.0f);
        float var  = ex2 - mean*mean;
        float o = (v[r]-mean) * rsqrtf(var + 1e-5f) * gwv + gbv;
        out[(m0+r)*D_+t] = o;
        if (outq_bf) outq_bf[(m0+r)*D_+t] = f2bf_bits(o + qp[(m0+r)*D_+t]);
        if (out_bf)  out_bf[(m0+r)*D_+t]  = f2bf_bits(o);
    }
}

// ---------------- 4b. sampling epilogue: loc from so_out, softmax(aw logits) -----
__global__ __launch_bounds__(256) void samp_epi_kernel(
    const float* __restrict__ so, const float* __restrict__ awl,
    const float* __restrict__ refp,
    float* __restrict__ loc_out, float* __restrict__ aw_out)
{
    __shared__ float lg[8][128];
    const int t = threadIdx.x, m0 = blockIdx.x * 8;
    for (int i = t; i < 8*128; i += 256) lg[i >> 7][i & 127] = awl[m0*128 + i];
    __syncthreads();
    const int c_ = t & 1, l_ = (t >> 3) & 3;
    float nrm;
    if (c_ == 0) nrm = (l_==0)?152.f:(l_==1)?76.f:(l_==2)?38.f:19.f;
    else         nrm = (l_==0)?100.f:(l_==1)?50.f:(l_==2)?25.f:13.f;
#pragma unroll
    for (int r = 0; r < 8; ++r) {
        const int m = m0 + r;
        loc_out[m*256 + t] = refp[(m*NL_ + l_)*2 + c_] + so[m*256 + t] / nrm;
    }
    if (t < 128) {
        const int g0 = (t >> 4) << 4;
        for (int r = 0; r < 8; ++r) {
            float mx = -1e30f;
            for (int j = 0; j < 16; ++j) mx = fmaxf(mx, lg[r][g0+j]);
            float s = 0.f;
            for (int j = 0; j < 16; ++j) s += __expf(lg[r][g0+j] - mx);
            aw_out[(m0+r)*128 + t] = __expf(lg[r][t] - mx) / s;
        }
    }
}

// ---------------- 5. deformable sampling gather (bf16), R5-proven ----------------
__global__ __launch_bounds__(256) void samp_fuse_bf16_kernel(
    const unsigned short* __restrict__ vbf,
    const float* __restrict__ loc_f, const float* __restrict__ aw_f,
    float* __restrict__ svec_g, float* __restrict__ wsum_g)
{
    __shared__ int   cidx[128][4];
    __shared__ float cwt[128][4];
    const int m = blockIdx.x, t = threadIdx.x;
    const int b = m / LQ_;

    if (t < 128) {   // t = h*16 + l*4 + p
        const int l = (t >> 2) & 3;
        const int HS[4] = {100,50,25,13}, WS[4] = {152,76,38,19}, S0[4] = {0,15200,19000,19950};
        const int Hh = HS[l], Ww = WS[l], s0 = S0[l];
        const float aw = aw_f[m*128 + t];
        const float x = loc_f[m*256 + 2*t]*Ww - 0.5f;
        const float y = loc_f[m*256 + 2*t + 1]*Hh - 0.5f;
        const float x0f = floorf(x), y0f = floorf(y);
        const int x0 = (int)x0f, y0 = (int)y0f;
        const float fx = x - x0f, fy = y - y0f;
        const int   cx[4] = {x0, x0+1, x0,   x0+1};
        const int   cy[4] = {y0, y0,   y0+1, y0+1};
        const float cw[4] = {(1.f-fx)*(1.f-fy), fx*(1.f-fy), (1.f-fx)*fy, fx*fy};
        float sw = 0.f;
#pragma unroll
        for (int j = 0; j < 4; ++j) {
            const bool valid = (cx[j] >= 0) & (cx[j] < Ww) & (cy[j] >= 0) & (cy[j] < Hh);
            cidx[t][j] = valid ? (s0 + cy[j]*Ww + cx[j]) : s0;
            float wv = valid ? aw*cw[j] : 0.f;
            cwt[t][j] = wv;
            sw += wv;
        }
#pragma unroll
        for (int off = 8; off; off >>= 1) sw += __shfl_xor(sw, off);
        if ((t & 15) == 0) wsum_g[m*NH_ + (t >> 4)] = sw;
    }
    __syncthreads();

    const int hh = (t >> 7) * 4;
    const int c  = t & 127;
    const unsigned int* sb = (const unsigned int*)(vbf + (size_t)b*LV_*D_) + c;
#pragma unroll
    for (int h = hh; h < hh + 4; ++h) {
        float e0=0.f, e1=0.f, e2=0.f, e3=0.f;
        float o0=0.f, o1=0.f, o2=0.f, o3=0.f;
#pragma unroll 4
        for (int s = 0; s < 16; ++s) {
            const int base = h*16 + s;
            const int   i0 = cidx[base][0], i1 = cidx[base][1],
                        i2 = cidx[base][2], i3 = cidx[base][3];
            const float w0 = cwt[base][0], w1 = cwt[base][1],
                        w2 = cwt[base][2], w3 = cwt[base][3];
            const unsigned int u0 = sb[(size_t)i0*128];
            const unsigned int u1 = sb[(size_t)i1*128];
            const unsigned int u2 = sb[(size_t)i2*128];
            const unsigned int u3 = sb[(size_t)i3*128];
            e0 += w0*lo2f(u0); o0 += w0*hi2f(u0);
            e1 += w1*lo2f(u1); o1 += w1*hi2f(u1);
            e2 += w2*lo2f(u2); o2 += w2*hi2f(u2);
            e3 += w3*lo2f(u3); o3 += w3*hi2f(u3);
        }
        *(float2*)&svec_g[(size_t)m*(NH_*D_) + h*D_ + 2*c] =
            make_float2((e0+e1)+(e2+e3), (o0+o1)+(o2+o3));
    }
}

// ---------------- 5c. per-head value projection (packed fp32 weights) -> bf16 ----
__global__ __launch_bounds__(256) void vproj_kernel(
    const float* __restrict__ svec_g, const float* __restrict__ wsum_g,
    const float4* __restrict__ vpwP, const float* __restrict__ vpb,
    unsigned short* __restrict__ vo_bf)
{
    __shared__ float sv[4][NH_*D_];    // 32 KB
    const int t = threadIdx.x, m0 = blockIdx.x * 4;
    for (int i = t; i < 4*NH_*D_; i += 256)
        sv[i >> 11][i & 2047] = svec_g[(size_t)m0*(NH_*D_) + i];
    __syncthreads();
    const int h = t >> 5;
    const float4* w4 = vpwP + t;
    float a0 = 0.f, a1 = 0.f, a2 = 0.f, a3 = 0.f;
    for (int c = 0; c < 64; ++c) {
        const float4 wq = w4[c*256];
        const float4 s0 = *(const float4*)&sv[0][h*D_ + c*4];
        const float4 s1 = *(const float4*)&sv[1][h*D_ + c*4];
        const float4 s2 = *(const float4*)&sv[2][h*D_ + c*4];
        const float4 s3 = *(const float4*)&sv[3][h*D_ + c*4];
        a0 += wq.x*s0.x + wq.y*s0.y + wq.z*s0.z + wq.w*s0.w;
        a1 += wq.x*s1.x + wq.y*s1.y + wq.z*s1.z + wq.w*s1.w;
        a2 += wq.x*s2.x + wq.y*s2.y + wq.z*s2.z + wq.w*s2.w;
        a3 += wq.x*s3.x + wq.y*s3.y + wq.z*s3.z + wq.w*s3.w;
    }
    const float bb = vpb[t];
    vo_bf[(size_t)(m0+0)*D_ + t] = f2bf_bits(a0 + bb*wsum_g[(m0+0)*NH_ + h]);
    vo_bf[(size_t)(m0+1)*D_ + t] = f2bf_bits(a1 + bb*wsum_g[(m0+1)*NH_ + h]);
    vo_bf[(size_t)(m0+2)*D_ + t] = f2bf_bits(a2 + bb*wsum_g[(m0+2)*NH_ + h]);
    vo_bf[(size_t)(m0+3)*D_ + t] = f2bf_bits(a3 + bb*wsum_g[(m0+3)*NH_ + h]);
}

extern "C" void kernel_launch(void* const* d_in, const int* in_sizes, int n_in,
                              void* d_out, int out_size, void* d_ws, size_t ws_size,
                              hipStream_t stream) {
    (void)in_sizes; (void)n_in; (void)out_size; (void)ws_size;
    const float* tgt  = (const float*)d_in[0];
    const float* qpos = (const float*)d_in[1];
    const float* refp = (const float*)d_in[2];
    const float* srcp = (const float*)d_in[3];
    const float* ipw  = (const float*)d_in[4];
    const float* ipb  = (const float*)d_in[5];
    const float* opw  = (const float*)d_in[6];
    const float* opb  = (const float*)d_in[7];
    const float* sow  = (const float*)d_in[8];
    const float* sob  = (const float*)d_in[9];
    const float* aww  = (const float*)d_in[10];
    const float* awb  = (const float*)d_in[11];
    const float* vpw  = (const float*)d_in[12];
    const float* vpb  = (const float*)d_in[13];
    const float* outw = (const float*)d_in[14];
    const float* outb = (const float*)d_in[15];
    const float* l1w  = (const float*)d_in[16];
    const float* l1b  = (const float*)d_in[17];
    const float* l2w  = (const float*)d_in[18];
    const float* l2b  = (const float*)d_in[19];
    const float* n1w  = (const float*)d_in[20];
    const float* n1b  = (const float*)d_in[21];
    const float* n2w  = (const float*)d_in[22];
    const float* n2b  = (const float*)d_in[23];
    const float* n3w  = (const float*)d_in[24];
    const float* n3b  = (const float*)d_in[25];

    // ---- workspace layout (floats), audited: all regions disjoint ----
    float* wsf = (float*)d_ws;
    float* qh   = wsf;                        //       0 .. 614400
    float* kh   = wsf + 614400;               //  614400 .. 1228800
    float* vh   = wsf + 1228800;              // 1228800 .. 1843200
    float* x1   = wsf + 1843200;              // 1843200 .. 2457600
    float* x2   = wsf + 2457600;              // 2457600 .. 3072000
    float* y    = wsf + 3072000;              // 3072000 .. 3686400 (shared GEMM fp32 out)
    float* so_o = wsf + 3686400;              // 3686400 .. 4300800
    float* awl  = wsf + 4300800;              // 4300800 .. 4608000 (2400*128)
    unsigned short* hid_bf  = (unsigned short*)(wsf + 4608000);  // 1,245,184 f (MPAD_*1024 u16)
    unsigned short* tgt_bf  = (unsigned short*)(wsf + 5853184);  // 311,296 f
    unsigned short* qk_bf   = (unsigned short*)(wsf + 6164480);  // 311,296 f
    unsigned short* sa_bf   = (unsigned short*)(wsf + 6475776);  // 311,296 f
    unsigned short* x1q_bf  = (unsigned short*)(wsf + 6787072);  // 311,296 f
    unsigned short* vo_bf   = (unsigned short*)(wsf + 7098368);  // 311,296 f
    unsigned short* x2_bf   = (unsigned short*)(wsf + 7409664);  // 311,296 f
    unsigned short* ipw_bf  = (unsigned short*)(wsf + 7720960);  //  98,304 f
    unsigned short* l1w_bf  = (unsigned short*)(wsf + 7819264);  // 131,072 f
    unsigned short* l2w_bf  = (unsigned short*)(wsf + 7950336);  // 131,072 f
    unsigned short* opw_bf  = (unsigned short*)(wsf + 8081408);  //  32,768 f
    unsigned short* outw_bf = (unsigned short*)(wsf + 8114176);  //  32,768 f
    unsigned short* sow_bf  = (unsigned short*)(wsf + 8146944);  //  32,768 f
    unsigned short* aww_bf  = (unsigned short*)(wsf + 8179712);  //  16,384 f
    float4* vpwP = (float4*)(wsf + 8196096);                     //  65,536 f
    unsigned short* vbf = (unsigned short*)(wsf + 8261632);      // 20,681,728 f
    float* svec_g = wsf + 8261632 + 20681728;                    // = 28,943,360 (4,915,200 f)
    float* wsum_g = svec_g + 4915200;                            // 33,858,560 (19,200 f) end 33,877,760

    float* xout   = (float*)d_out;            // x   (8,300,256)
    float* locout = xout + 614400;            // loc (8,300,8,4,4,2)
    float* awout  = xout + 1228800;           // aw  (8,300,8,4,4)

    cvt_misc_kernel<<<1528, 256, 0, stream>>>(
        (const float4*)tgt, (const float4*)qpos, (const float4*)ipw,
        (const float4*)l1w, (const float4*)l2w, (const float4*)opw,
        (const float4*)outw, (const float4*)sow, (const float4*)aww,
        (ushort4*)tgt_bf, (ushort4*)qk_bf, (ushort4*)ipw_bf,
        (ushort4*)l1w_bf, (ushort4*)l2w_bf, (ushort4*)opw_bf,
        (ushort4*)outw_bf, (ushort4*)sow_bf, (ushort4*)aww_bf);
    pack_vpw_kernel<<<16, 256, 0, stream>>>((const float4*)vpw, vpwP);
    cvt_bf16_kernel<<<2048, 256, 0, stream>>>(srcp, vbf);

    // QKV: three N=256 GEMMs
    gemm_bf16_kernel<<<dim3(38, 4), 256, 0, stream>>>(qk_bf,  ipw_bf,          ipb,       qh, nullptr, 256, 256, 0);
    gemm_bf16_kernel<<<dim3(38, 4), 256, 0, stream>>>(qk_bf,  ipw_bf + 65536,  ipb + 256, kh, nullptr, 256, 256, 0);
    gemm_bf16_kernel<<<dim3(38, 4), 256, 0, stream>>>(tgt_bf, ipw_bf + 131072, ipb + 512, vh, nullptr, 256, 256, 0);

    attn_kernel<<<dim3(BS_*NH_, 5), 256, 0, stream>>>(qh, kh, vh, sa_bf);

    // out-proj + LN1 (norm2 in ref naming): x1 = LN(sa@opw^T + opb + tgt)
    gemm_bf16_kernel<<<dim3(38, 4), 256, 0, stream>>>(sa_bf, opw_bf, opb, y, nullptr, 256, 256, 0);
    res_ln_kernel<<<NQ_/8, 256, 0, stream>>>(y, tgt, n2w, n2b, x1, qpos, x1q_bf, nullptr);

    // sampling params: two GEMMs + epilogue
    gemm_bf16_kernel<<<dim3(38, 4), 256, 0, stream>>>(x1q_bf, sow_bf, sob, so_o, nullptr, 256, 256, 0);
    gemm_bf16_kernel<<<dim3(38, 2), 256, 0, stream>>>(x1q_bf, aww_bf, awb, awl, nullptr, 256, 128, 0);
    samp_epi_kernel<<<NQ_/8, 256, 0, stream>>>(so_o, awl, refp, locout, awout);

    samp_fuse_bf16_kernel<<<NQ_, 256, 0, stream>>>(vbf, locout, awout, svec_g, wsum_g);
    vproj_kernel<<<NQ_/4, 256, 0, stream>>>(svec_g, wsum_g, vpwP, vpb, vo_bf);

    // output-proj + LN2 (norm1): x2 = LN(vo@outw^T + outb + x1)
    gemm_bf16_kernel<<<dim3(38, 4), 256, 0, stream>>>(vo_bf, outw_bf, outb, y, nullptr, 256, 256, 0);
    res_ln_kernel<<<NQ_/8, 256, 0, stream>>>(y, x1, n1w, n1b, x2, nullptr, nullptr, x2_bf);

    // FFN via MFMA + final LN (norm3)
    gemm_bf16_kernel<<<dim3(38, 16), 256, 0, stream>>>(x2_bf,  l1w_bf, l1b, nullptr, hid_bf, 256, 1024, 1);
    gemm_bf16_kernel<<<dim3(38, 4),  256, 0, stream>>>(hid_bf, l2w_bf, l2b, y, nullptr, 1024, 256, 0);
    res_ln_kernel<<<NQ_/8, 256, 0, stream>>>(y, x2, n3w, n3b, xout, nullptr, nullptr, nullptr);
}